// Round 4
// baseline (3289.148 us; speedup 1.0000x reference)
//
#include <hip/hip_runtime.h>
#include <hip/hip_bf16.h>
#include <math.h>

#define N_NODES 60000
#define E_EDGES 200000
#define DIM     128
#define NINPK   256
#define TSTEPS  6
#define LLAYERS 2
#define BGRAPH  16
#define NBINS   (TSTEPS * N_NODES)          // 360000
#define NB      ((NBINS + 1023) / 1024)     // 352 scan blocks

typedef float f32x4 __attribute__((ext_vector_type(4)));
typedef short s16x8 __attribute__((ext_vector_type(8)));

static __device__ __forceinline__ float sigm(float x) { return 1.f / (1.f + expf(-x)); }

// round-to-nearest-even float -> bf16 bits
static __device__ __forceinline__ short f2bf(float f) {
  unsigned u = __float_as_uint(f);
  u += 0x7FFFu + ((u >> 16) & 1u);
  return (short)(u >> 16);
}

// order-preserving float <-> uint for atomicMax-based segment max
static __device__ __forceinline__ unsigned fenc(float f) {
  unsigned u = __float_as_uint(f);
  return (u & 0x80000000u) ? ~u : (u | 0x80000000u);
}
static __device__ __forceinline__ float fdec(unsigned u) {
  u = (u & 0x80000000u) ? (u & 0x7fffffffu) : ~u;
  return __uint_as_float(u);
}

// meta layout: [0..5]=edge cnt per t  [8..13]=first  [32..37]=segcnt  [40..45]=zcnt
// ---------------- init ----------------
__global__ void k_init(const float* __restrict__ gcn, float* __restrict__ hx,
                       float* __restrict__ cx, int* __restrict__ meta,
                       unsigned* __restrict__ keys, int* __restrict__ hist,
                       int* __restrict__ rowof, unsigned char* __restrict__ flag) {
  int i = blockIdx.x * blockDim.x + threadIdx.x;
  if (i < LLAYERS * DIM * DIM) { hx[i] = gcn[i]; cx[i] = 0.f; }
  if (i < BGRAPH * DIM) keys[i] = 0u;
  if (i < 64) meta[i] = 0;
  if (i < NBINS) { hist[i] = 0; rowof[i] = -1; flag[i] = 0; }
}

// ---------------- histogram by (t,dst); mark src flags; per-t edge counts ----------------
__global__ void k_hist(const int* __restrict__ et, const int* __restrict__ src,
                       const int* __restrict__ dst, int* __restrict__ hist,
                       unsigned char* __restrict__ flag, int* __restrict__ meta) {
  __shared__ int loc[TSTEPS];
  int tid = threadIdx.x;
  if (tid < TSTEPS) loc[tid] = 0;
  __syncthreads();
  int e = blockIdx.x * blockDim.x + tid;
  if (e < E_EDGES) {
    int t = et[e];
    atomicAdd(&hist[t * N_NODES + dst[e]], 1);
    flag[t * N_NODES + src[e]] = 1;
    atomicAdd(&loc[t], 1);
  }
  __syncthreads();
  if (tid < TSTEPS && loc[tid]) atomicAdd(&meta[tid], loc[tid]);
}

// ---------------- 2-level exclusive scan over hist (360000) ----------------
__global__ void k_scan1(const int* __restrict__ in, int* __restrict__ out,
                        int* __restrict__ bsum) {
  __shared__ int sh[256];
  int b0 = blockIdx.x * 1024;
  int tid = threadIdx.x;
  int v[4]; int s = 0;
#pragma unroll
  for (int q = 0; q < 4; ++q) {
    int i = b0 + tid * 4 + q;
    v[q] = (i < NBINS) ? in[i] : 0;
    s += v[q];
  }
  sh[tid] = s;
  __syncthreads();
  for (int off = 1; off < 256; off <<= 1) {
    int x = (tid >= off) ? sh[tid - off] : 0;
    __syncthreads();
    sh[tid] += x;
    __syncthreads();
  }
  int ex = sh[tid] - s;
#pragma unroll
  for (int q = 0; q < 4; ++q) {
    int i = b0 + tid * 4 + q;
    if (i < NBINS) out[i] = ex;
    ex += v[q];
  }
  if (tid == 255) bsum[blockIdx.x] = sh[255];
}

__global__ void k_scan2(int* __restrict__ bsum, int* __restrict__ meta) {
  if (blockIdx.x == 0 && threadIdx.x == 0) {
    int s = 0;
    for (int i = 0; i < NB; ++i) { int v = bsum[i]; bsum[i] = s; s += v; }
    int f = 0;
    for (int t = 0; t < TSTEPS; ++t) { meta[8 + t] = f; f |= (meta[t] > 0); }
  }
}

// finalize scan; build segments (one per nonempty (t,dst) bin) + rowof map
__global__ void k_scan3seg(int* __restrict__ scanv, const int* __restrict__ bsum,
                           const int* __restrict__ hist, int* __restrict__ meta,
                           int* __restrict__ segdst, int* __restrict__ segstart,
                           int* __restrict__ seglen, int* __restrict__ rowof) {
  int i = blockIdx.x * blockDim.x + threadIdx.x;
  if (i >= NBINS) return;
  int v = scanv[i] + bsum[i >> 10];
  scanv[i] = v;
  int c = hist[i];
  if (c > 0) {
    int t = i / N_NODES;
    int d = i - t * N_NODES;
    int sidx = atomicAdd(&meta[32 + t], 1);
    long sb = (long)t * N_NODES + sidx;
    segdst[sb] = d;
    segstart[sb] = v;
    seglen[sb] = c;
    rowof[i] = sidx;
  }
}

// place edges into sorted order (scanv used as destructive cursor)
__global__ void k_place(const int* __restrict__ et, const int* __restrict__ src,
                        const int* __restrict__ dst, const float* __restrict__ ew,
                        int* __restrict__ scanv, int* __restrict__ ssrc,
                        float* __restrict__ sew) {
  int e = blockIdx.x * blockDim.x + threadIdx.x;
  if (e >= E_EDGES) return;
  int bin = et[e] * N_NODES + dst[e];
  int pos = atomicAdd(&scanv[bin], 1);
  ssrc[pos] = src[e];
  sew[pos] = ew[e];
}

// src-only touched nodes (flagged as src, not in dst set) -> zero list
__global__ void k_zlist(const unsigned char* __restrict__ flag,
                        const int* __restrict__ rowof, int* __restrict__ meta,
                        int* __restrict__ zlist) {
  int i = blockIdx.x * blockDim.x + threadIdx.x;
  if (i >= NBINS) return;
  if (flag[i] && rowof[i] < 0) {
    int t = i / N_NODES;
    int zi = atomicAdd(&meta[40 + t], 1);
    zlist[(long)t * N_NODES + zi] = i - t * N_NODES;
  }
}

// ---------------- LSTM part 1: g0 = x@Wih^T + b, g1 = x@(Wih+Whh)^T + b ----------------
__global__ void k_lstm_g(const float* __restrict__ hx, const float* __restrict__ Wih,
                         const float* __restrict__ Whh, const float* __restrict__ bih,
                         const float* __restrict__ bhh, float* __restrict__ g0,
                         float* __restrict__ g1) {
  int i = blockIdx.x >> 9;          // layer
  int c = blockIdx.x & 511;         // gate column 0..511
  int r = threadIdx.x;              // 0..127
  __shared__ float wi[DIM], wh[DIM];
  wi[r] = Wih[((long)i * 4 * DIM + c) * DIM + r];
  wh[r] = Whh[((long)i * 4 * DIM + c) * DIM + r];
  __syncthreads();
  const float* x = hx + ((long)i * DIM + r) * DIM;
  float a = 0.f, b = 0.f;
#pragma unroll 8
  for (int k = 0; k < DIM; ++k) {
    a = fmaf(x[k], wi[k], a);
    b = fmaf(x[k], wh[k], b);
  }
  float base = bih[i * 4 * DIM + c] + bhh[i * 4 * DIM + c];
  long o = ((long)i * 4 * DIM + c) * DIM + r;
  g0[o] = a + base;
  g1[o] = a + b + base;
}

// ---------------- LSTM part 2: gate nonlinearities + select ----------------
__global__ void k_lstm_upd(float* __restrict__ hx, float* __restrict__ cx,
                           const float* __restrict__ g0, const float* __restrict__ g1,
                           const int* __restrict__ meta, int t) {
  int idx = blockIdx.x * blockDim.x + threadIdx.x;
  if (idx >= LLAYERS * DIM * DIM) return;
  int i = idx >> 14;
  int rem = idx & 16383;
  int r = rem >> 7, j = rem & 127;
  long gb = (long)i * 4 * DIM * DIM;
  float gi0 = g0[gb + (0 * DIM + j) * DIM + r];
  float gg0 = g0[gb + (2 * DIM + j) * DIM + r];
  float go0 = g0[gb + (3 * DIM + j) * DIM + r];
  float gi1 = g1[gb + (0 * DIM + j) * DIM + r];
  float gf1 = g1[gb + (1 * DIM + j) * DIM + r];
  float gg1 = g1[gb + (2 * DIM + j) * DIM + r];
  float go1 = g1[gb + (3 * DIM + j) * DIM + r];
  float c_zero = sigm(gi0) * tanhf(gg0);
  float h_zero = sigm(go0) * tanhf(c_zero);
  float c0v = cx[idx];
  float c_st = sigm(gf1) * c0v + sigm(gi1) * tanhf(gg1);
  float h_st = sigm(go1) * tanhf(c_st);
  int first = meta[8 + t];
  int has = meta[t] > 0;
  float hold = hx[idx];
  float hi_v = first ? h_st : h_zero;
  float ci_v = first ? c0v : c_zero;
  hx[idx] = has ? hi_v : hold;
  cx[idx] = has ? ci_v : c0v;
}

// ---------------- weight prep: fp32 [K][128] -> bf16 [kb][c][g-swizzled][8] ----------------
__global__ void k_prep(const float* __restrict__ W, short* __restrict__ Wt, int K) {
  int idx = blockIdx.x * blockDim.x + threadIdx.x;
  int total = (K >> 6) * DIM * 8;
  if (idx >= total) return;
  int g = idx & 7;
  int c = (idx >> 3) & 127;
  int kb = idx >> 10;
  s16x8 s;
#pragma unroll
  for (int j = 0; j < 8; ++j) s[j] = f2bf(W[(long)(kb * 64 + g * 8 + j) * DIM + c]);
  *(s16x8*)&Wt[(((long)kb * DIM + c) * 8 + (g ^ (c & 7))) * 8] = s;
}

// ---------------- segmented scatter: Spack[s] = sum_e w_e * IN[src_e] ----------------
// one 32-lane group per segment; plain stores, no atomics.
template <bool PACKEDIN>
__global__ void k_segscat(const int* __restrict__ segstart, const int* __restrict__ seglen,
                          const int* __restrict__ ssrc, const float* __restrict__ sew,
                          const float* __restrict__ IN, const int* __restrict__ rowof,
                          float* __restrict__ Spack, const int* __restrict__ nsegp) {
  int nseg = nsegp[0];
  int gsz = gridDim.x * (blockDim.x >> 5);
  int l = threadIdx.x & 31;
  int d4 = l << 2;
  for (int s = blockIdx.x * (blockDim.x >> 5) + (threadIdx.x >> 5); s < nseg; s += gsz) {
    int st = segstart[s], len = seglen[s];
    float4 acc = make_float4(0.f, 0.f, 0.f, 0.f);
    for (int e = st; e < st + len; ++e) {
      float w = sew[e];
      int sn = ssrc[e];
      const float* base;
      if (PACKEDIN) {
        int pr = rowof[sn];
        if (pr < 0) continue;
        base = IN + (long)pr * DIM;
      } else {
        base = IN + (long)sn * DIM;
      }
      const float4 hv = *reinterpret_cast<const float4*>(base + d4);
      acc.x = fmaf(w, hv.x, acc.x);
      acc.y = fmaf(w, hv.y, acc.y);
      acc.z = fmaf(w, hv.z, acc.z);
      acc.w = fmaf(w, hv.w, acc.w);
    }
    *reinterpret_cast<float4*>(Spack + (long)s * DIM + d4) = acc;
  }
}

// ---------------- MFMA GEMM: C[n][c] = act(sum_k A[row(n)][k] * W[k][c] (+bias)) ----
template <int KTILES, bool GATHER, bool RELU, bool BIAS, bool DYN>
__global__ __launch_bounds__(256) void k_gemm_mfma(const float* __restrict__ A,
                                                   const int* __restrict__ rowids,
                                                   const short* __restrict__ Wt,
                                                   const float* __restrict__ bias,
                                                   float* __restrict__ C, int Nc,
                                                   const int* __restrict__ nptr) {
  const int N = DYN ? nptr[0] : Nc;
  const int n0 = blockIdx.x * 128;
  if (n0 >= N) return;
  __shared__ short As[128 * 64];
  __shared__ short Ws[128 * 64];
  __shared__ int rid[128];
  const int tid = threadIdx.x;
  if (GATHER) {
    if (tid < 128) {
      int n = n0 + tid;
      rid[tid] = (n < N) ? rowids[n] * (KTILES * 64) : 0;
    }
  }
  const int lane = tid & 63;
  const int w = tid >> 6;
  f32x4 acc[2][8] = {};
  for (int kt = 0; kt < KTILES; ++kt) {
    __syncthreads();  // rid ready (kt=0) / previous compute done
#pragma unroll
    for (int p = 0; p < 4; ++p) {
      int gi = p * 256 + tid;
      int row = gi >> 3, g = gi & 7;
      int n = n0 + row;
      float4 v0 = make_float4(0.f, 0.f, 0.f, 0.f), v1 = v0;
      if (n < N) {
        long base = GATHER ? (long)rid[row] : (long)n * (KTILES * 64);
        const float* ap = A + base + kt * 64 + g * 8;
        v0 = *reinterpret_cast<const float4*>(ap);
        v1 = *reinterpret_cast<const float4*>(ap + 4);
      }
      s16x8 s;
      s[0] = f2bf(v0.x); s[1] = f2bf(v0.y); s[2] = f2bf(v0.z); s[3] = f2bf(v0.w);
      s[4] = f2bf(v1.x); s[5] = f2bf(v1.y); s[6] = f2bf(v1.z); s[7] = f2bf(v1.w);
      *(s16x8*)&As[(row * 8 + (g ^ (row & 7))) * 8] = s;
    }
    const int4* wg = reinterpret_cast<const int4*>(Wt + kt * 128 * 64);
    int4* wl = reinterpret_cast<int4*>(Ws);
#pragma unroll
    for (int p = 0; p < 4; ++p) wl[p * 256 + tid] = wg[p * 256 + tid];
    __syncthreads();
#pragma unroll
    for (int kk = 0; kk < 2; ++kk) {
      int gb = kk * 4 + (lane >> 4);
      s16x8 a[2];
#pragma unroll
      for (int fr = 0; fr < 2; ++fr) {
        int row = w * 32 + fr * 16 + (lane & 15);
        a[fr] = *(const s16x8*)&As[(row * 8 + (gb ^ (row & 7))) * 8];
      }
#pragma unroll
      for (int fc = 0; fc < 8; ++fc) {
        int col = fc * 16 + (lane & 15);
        s16x8 b = *(const s16x8*)&Ws[(col * 8 + (gb ^ (col & 7))) * 8];
        acc[0][fc] = __builtin_amdgcn_mfma_f32_16x16x32_bf16(a[0], b, acc[0][fc], 0, 0, 0);
        acc[1][fc] = __builtin_amdgcn_mfma_f32_16x16x32_bf16(a[1], b, acc[1][fc], 0, 0, 0);
      }
    }
  }
  // epilogue: C/D layout col=lane&15, row=(lane>>4)*4+reg  [m89-verified]
  const int cb = lane & 15;
  const int rb = w * 32 + (lane >> 4) * 4;
#pragma unroll
  for (int fr = 0; fr < 2; ++fr) {
#pragma unroll
    for (int reg = 0; reg < 4; ++reg) {
      int n = n0 + rb + fr * 16 + reg;
      if (n >= N) continue;
      float* cp = C + (long)n * DIM;
#pragma unroll
      for (int fc = 0; fc < 8; ++fc) {
        float x = acc[fr][fc][reg];
        if (BIAS) x += bias[fc * 16 + cb];
        if (RELU) x = fmaxf(x, 0.f);
        cp[fc * 16 + cb] = x;
      }
    }
  }
}

// ---------------- writeback: h[segdst[s]] = P2[s]; h[zlist[z]] = 0 ----------------
__global__ void k_wb(float* __restrict__ h, const float* __restrict__ P2,
                     const int* __restrict__ segdst, const int* __restrict__ zlist,
                     const int* __restrict__ nsegp, const int* __restrict__ nzp) {
  int nseg = nsegp[0], nz = nzp[0];
  int total = nseg + nz;
  int gsz = gridDim.x * (blockDim.x >> 5);
  int l = threadIdx.x & 31;
  int d4 = l << 2;
  for (int s = blockIdx.x * (blockDim.x >> 5) + (threadIdx.x >> 5); s < total; s += gsz) {
    if (s < nseg) {
      int d = segdst[s];
      *reinterpret_cast<float4*>(h + (long)d * DIM + d4) =
          *reinterpret_cast<const float4*>(P2 + (long)s * DIM + d4);
    } else {
      int n = zlist[s - nseg];
      *reinterpret_cast<float4*>(h + (long)n * DIM + d4) = make_float4(0.f, 0.f, 0.f, 0.f);
    }
  }
}

// ---------------- segment max (graph_id sorted) ----------------
__global__ void k_segmax(const float* __restrict__ h, const int* __restrict__ gid,
                         unsigned* __restrict__ keys) {
  int d = threadIdx.x;  // 0..127
  int n0 = blockIdx.x * 64;
  int end = min(n0 + 64, N_NODES);
  if (n0 >= N_NODES) return;
  int curg = gid[n0];
  float m = -INFINITY;
  for (int n = n0; n < end; ++n) {
    int g = gid[n];
    if (g != curg) {
      atomicMax(&keys[(long)curg * DIM + d], fenc(m));
      curg = g;
      m = -INFINITY;
    }
    m = fmaxf(m, h[(long)n * DIM + d]);
  }
  atomicMax(&keys[(long)curg * DIM + d], fenc(m));
}

// ---------------- final: logits, probs, BCE loss ----------------
__global__ void k_final(const unsigned* __restrict__ keys, const float* __restrict__ outW,
                        const float* __restrict__ outB, const float* __restrict__ y,
                        float* __restrict__ out) {
  __shared__ float lt[BGRAPH];
  int tid = threadIdx.x;  // 64 threads: 4 per graph
  int b = tid >> 2, l4 = tid & 3;
  float s = 0.f;
  for (int d = l4; d < DIM; d += 4) {
    float v = fdec(keys[(long)b * DIM + d]);
    if (!isfinite(v)) v = 0.f;
    s += v * outW[d];
  }
  s += __shfl_down(s, 1);
  s += __shfl_down(s, 2);
  if (l4 == 0) {
    float l = s + outB[0];
    out[1 + b] = 1.f / (1.f + expf(-l));
    lt[b] = fmaxf(l, 0.f) - l * y[b] + log1pf(expf(-fabsf(l)));
  }
  __syncthreads();
  if (tid == 0) {
    float acc = 0.f;
    for (int i = 0; i < BGRAPH; ++i) acc += lt[i];
    out[0] = acc / (float)BGRAPH;
  }
}

extern "C" void kernel_launch(void* const* d_in, const int* in_sizes, int n_in,
                              void* d_out, int out_size, void* d_ws, size_t ws_size,
                              hipStream_t stream) {
  const int* word_ids = (const int*)d_in[0];
  const int* src = (const int*)d_in[1];
  const int* dst = (const int*)d_in[2];
  const int* et = (const int*)d_in[3];
  const float* ew = (const float*)d_in[4];
  const int* gid = (const int*)d_in[5];
  const float* y = (const float*)d_in[6];
  const float* wemb = (const float*)d_in[7];
  const float* adW = (const float*)d_in[8];
  const float* adb = (const float*)d_in[9];
  const float* gcn = (const float*)d_in[10];
  const float* Wih = (const float*)d_in[11];
  const float* Whh = (const float*)d_in[12];
  const float* bih = (const float*)d_in[13];
  const float* bhh = (const float*)d_in[14];
  const float* outW = (const float*)d_in[15];
  const float* outB = (const float*)d_in[16];
  float* out = (float*)d_out;

  char* ws = (char*)d_ws;
  const long ND = (long)N_NODES * DIM;  // 7,680,000 floats
  float* h = (float*)ws;        ws += ND * 4;            // dense node features
  float* P1 = (float*)ws;       ws += ND * 4;            // packed scatter out / GEMM in
  float* P2 = (float*)ws;       ws += ND * 4;            // packed GEMM out
  float* hx = (float*)ws;       ws += LLAYERS * DIM * DIM * 4;
  float* cx = (float*)ws;       ws += LLAYERS * DIM * DIM * 4;
  float* g0 = (float*)ws;       ws += LLAYERS * 4 * DIM * DIM * 4;
  float* g1 = (float*)ws;       ws += LLAYERS * 4 * DIM * DIM * 4;
  int* meta = (int*)ws;         ws += 64 * 4;
  unsigned* keys = (unsigned*)ws; ws += BGRAPH * DIM * 4;
  int* hist = (int*)ws;         ws += (long)NBINS * 4;
  int* scanv = (int*)ws;        ws += (long)NBINS * 4;
  int* bsum = (int*)ws;         ws += ((NB + 63) & ~63) * 4;
  int* rowof = (int*)ws;        ws += (long)NBINS * 4;
  int* segdst = (int*)ws;       ws += (long)NBINS * 4;
  int* segstart = (int*)ws;     ws += (long)NBINS * 4;
  int* seglen = (int*)ws;       ws += (long)NBINS * 4;
  int* zlist = (int*)ws;        ws += (long)NBINS * 4;
  int* ssrc = (int*)ws;         ws += (long)E_EDGES * 4;
  float* sew = (float*)ws;      ws += (long)E_EDGES * 4;
  unsigned char* flag = (unsigned char*)ws; ws += (NBINS + 63) & ~63;
  short* WtAd = (short*)ws;     ws += 4L * DIM * 64 * 2;
  short* WtL0 = (short*)ws;     ws += 2L * DIM * 64 * 2;
  short* WtL1 = (short*)ws;     ws += 2L * DIM * 64 * 2;

  const int binsblocks = (NBINS + 255) / 256;  // 1407
  const int gemm_blocks = (N_NODES + 127) / 128;

  // setup: sort edges by (t,dst), build segments, rowof, zero-lists
  k_init<<<binsblocks, 256, 0, stream>>>(gcn, hx, cx, meta, keys, hist, rowof, flag);
  k_hist<<<(E_EDGES + 255) / 256, 256, 0, stream>>>(et, src, dst, hist, flag, meta);
  k_scan1<<<NB, 256, 0, stream>>>(hist, scanv, bsum);
  k_scan2<<<1, 64, 0, stream>>>(bsum, meta);
  k_scan3seg<<<binsblocks, 256, 0, stream>>>(scanv, bsum, hist, meta, segdst,
                                             segstart, seglen, rowof);
  k_place<<<(E_EDGES + 255) / 256, 256, 0, stream>>>(et, src, dst, ew, scanv, ssrc, sew);
  k_zlist<<<binsblocks, 256, 0, stream>>>(flag, rowof, meta, zlist);
  k_prep<<<16, 256, 0, stream>>>(adW, WtAd, NINPK);

  // h0 = word_embeds[word_ids] @ adapt_W + adapt_b
  k_gemm_mfma<4, true, false, true, false><<<gemm_blocks, 256, 0, stream>>>(
      wemb, word_ids, WtAd, adb, h, N_NODES, nullptr);

  for (int t = 0; t < TSTEPS; ++t) {
    const int* nsegp = &meta[32 + t];
    const int* nzp = &meta[40 + t];
    const int* ss = segstart + (long)t * N_NODES;
    const int* sl = seglen + (long)t * N_NODES;
    const int* sd = segdst + (long)t * N_NODES;
    const int* ro = rowof + (long)t * N_NODES;
    const int* zl = zlist + (long)t * N_NODES;
    // LSTM weight evolution
    k_lstm_g<<<LLAYERS * 512, 128, 0, stream>>>(hx, Wih, Whh, bih, bhh, g0, g1);
    k_lstm_upd<<<128, 256, 0, stream>>>(hx, cx, g0, g1, meta, t);
    k_prep<<<8, 256, 0, stream>>>(hx, WtL0, DIM);
    k_prep<<<8, 256, 0, stream>>>(hx + DIM * DIM, WtL1, DIM);
    // GCN layer 0: P1 = segscatter(h), P2 = relu(P1 @ hx[0])
    k_segscat<false><<<512, 256, 0, stream>>>(ss, sl, ssrc, sew, h, ro, P1, nsegp);
    k_gemm_mfma<2, false, true, false, true><<<gemm_blocks, 256, 0, stream>>>(
        P1, nullptr, WtL0, nullptr, P2, 0, nsegp);
    // GCN layer 1: P1 = segscatter(P2 via rowof), P2 = relu(P1 @ hx[1])
    k_segscat<true><<<512, 256, 0, stream>>>(ss, sl, ssrc, sew, P2, ro, P1, nsegp);
    k_gemm_mfma<2, false, true, false, true><<<gemm_blocks, 256, 0, stream>>>(
        P1, nullptr, WtL1, nullptr, P2, 0, nsegp);
    // write back: h[dst-rows] = P2 rows; h[src-only touched] = 0
    k_wb<<<256, 256, 0, stream>>>(h, P2, sd, zl, nsegp, nzp);
  }

  k_segmax<<<(N_NODES + 63) / 64, 128, 0, stream>>>(h, gid, keys);
  k_final<<<1, 64, 0, stream>>>(keys, outW, outB, y, out);
}

// Round 5
// 573.074 us; speedup vs baseline: 5.7395x; 5.7395x over previous
//
#include <hip/hip_runtime.h>
#include <hip/hip_bf16.h>
#include <math.h>

#define N_NODES 60000
#define E_EDGES 200000
#define DIM     128
#define NINPK   256
#define TSTEPS  6
#define LLAYERS 2
#define BGRAPH  16
#define NBINS   (TSTEPS * N_NODES)          // 360000
#define NB      ((NBINS + 1023) / 1024)     // 352 scan blocks

typedef float f32x4 __attribute__((ext_vector_type(4)));
typedef short s16x8 __attribute__((ext_vector_type(8)));

static __device__ __forceinline__ float sigm(float x) { return 1.f / (1.f + expf(-x)); }

// round-to-nearest-even float -> bf16 bits
static __device__ __forceinline__ short f2bf(float f) {
  unsigned u = __float_as_uint(f);
  u += 0x7FFFu + ((u >> 16) & 1u);
  return (short)(u >> 16);
}

// order-preserving float <-> uint for atomicMax-based segment max
static __device__ __forceinline__ unsigned fenc(float f) {
  unsigned u = __float_as_uint(f);
  return (u & 0x80000000u) ? ~u : (u | 0x80000000u);
}
static __device__ __forceinline__ float fdec(unsigned u) {
  u = (u & 0x80000000u) ? (u & 0x7fffffffu) : ~u;
  return __uint_as_float(u);
}

// meta: [0..5]=edge cnt/t [8..13]=first [32..37]=segcnt [40..45]=zcnt [48..53]=seg rank base
// ---------------- init ----------------
__global__ void k_init(const float* __restrict__ gcn, float* __restrict__ hx,
                       float* __restrict__ cx, int* __restrict__ meta,
                       unsigned* __restrict__ keys, int* __restrict__ hist,
                       int* __restrict__ rowof, unsigned char* __restrict__ flag) {
  int i = blockIdx.x * blockDim.x + threadIdx.x;
  if (i < LLAYERS * DIM * DIM) { hx[i] = gcn[i]; cx[i] = 0.f; }
  if (i < BGRAPH * DIM) keys[i] = 0u;
  if (i < 64) meta[i] = 0;
  if (i < NBINS) { hist[i] = 0; rowof[i] = -1; flag[i] = 0; }
}

// ---------------- histogram by (t,dst); mark src flags; per-t edge counts ----------------
__global__ void k_hist(const int* __restrict__ et, const int* __restrict__ src,
                       const int* __restrict__ dst, int* __restrict__ hist,
                       unsigned char* __restrict__ flag, int* __restrict__ meta) {
  __shared__ int loc[TSTEPS];
  int tid = threadIdx.x;
  if (tid < TSTEPS) loc[tid] = 0;
  __syncthreads();
  int e = blockIdx.x * blockDim.x + tid;
  if (e < E_EDGES) {
    int t = et[e];
    atomicAdd(&hist[t * N_NODES + dst[e]], 1);
    flag[t * N_NODES + src[e]] = 1;
    atomicAdd(&loc[t], 1);
  }
  __syncthreads();
  if (tid < TSTEPS && loc[tid]) atomicAdd(&meta[tid], loc[tid]);
}

// ---------------- fused 2-level exclusive scan: hist values AND nonempty indicator ----
__global__ void k_scan1b(const int* __restrict__ hist, int* __restrict__ scanv,
                         int* __restrict__ scans, int* __restrict__ bsumA,
                         int* __restrict__ bsumB) {
  __shared__ int shA[256], shB[256];
  int b0 = blockIdx.x * 1024;
  int tid = threadIdx.x;
  int v[4], w[4]; int sA = 0, sB = 0;
#pragma unroll
  for (int q = 0; q < 4; ++q) {
    int i = b0 + tid * 4 + q;
    int c = (i < NBINS) ? hist[i] : 0;
    v[q] = c; w[q] = (c > 0) ? 1 : 0;
    sA += c; sB += w[q];
  }
  shA[tid] = sA; shB[tid] = sB;
  __syncthreads();
  for (int off = 1; off < 256; off <<= 1) {
    int xA = (tid >= off) ? shA[tid - off] : 0;
    int xB = (tid >= off) ? shB[tid - off] : 0;
    __syncthreads();
    shA[tid] += xA; shB[tid] += xB;
    __syncthreads();
  }
  int exA = shA[tid] - sA, exB = shB[tid] - sB;
#pragma unroll
  for (int q = 0; q < 4; ++q) {
    int i = b0 + tid * 4 + q;
    if (i < NBINS) { scanv[i] = exA; scans[i] = exB; }
    exA += v[q]; exB += w[q];
  }
  if (tid == 255) { bsumA[blockIdx.x] = shA[255]; bsumB[blockIdx.x] = shB[255]; }
}

// prefix both block-sum arrays; first flags; per-t segment counts + rank bases
__global__ void k_scan2(int* __restrict__ bsumA, int* __restrict__ bsumB,
                        const int* __restrict__ scans, int* __restrict__ meta) {
  if (blockIdx.x == 0 && threadIdx.x == 0) {
    int sA = 0, sB = 0;
    for (int i = 0; i < NB; ++i) {
      int a = bsumA[i]; bsumA[i] = sA; sA += a;
      int b = bsumB[i]; bsumB[i] = sB; sB += b;
    }
    int f = 0;
    for (int t = 0; t < TSTEPS; ++t) { meta[8 + t] = f; f |= (meta[t] > 0); }
    for (int t = 0; t < TSTEPS; ++t) {
      int lo = scans[t * N_NODES] + bsumB[(t * N_NODES) >> 10];
      int hi = (t == TSTEPS - 1)
                   ? sB
                   : scans[(t + 1) * N_NODES] + bsumB[((t + 1) * N_NODES) >> 10];
      meta[32 + t] = hi - lo;   // segment count
      meta[48 + t] = lo;        // rank base
    }
  }
}

// finalize edge-offset scan; build segments via scan ranks (NO atomics)
__global__ void k_scan3seg(int* __restrict__ scanv, const int* __restrict__ bsumA,
                           const int* __restrict__ scans, const int* __restrict__ bsumB,
                           const int* __restrict__ hist, const int* __restrict__ meta,
                           int* __restrict__ segdst, int* __restrict__ segstart,
                           int* __restrict__ seglen, int* __restrict__ rowof) {
  int i = blockIdx.x * blockDim.x + threadIdx.x;
  if (i >= NBINS) return;
  int vA = scanv[i] + bsumA[i >> 10];
  scanv[i] = vA;
  int c = hist[i];
  if (c > 0) {
    int t = i / N_NODES;
    int tb = t * N_NODES;
    int sidx = scans[i] + bsumB[i >> 10] - meta[48 + t];
    long sb = (long)tb + sidx;
    segdst[sb] = i - tb;
    segstart[sb] = vA;
    seglen[sb] = c;
    rowof[i] = sidx;
  }
}

// place edges into sorted order (scanv used as destructive cursor)
__global__ void k_place(const int* __restrict__ et, const int* __restrict__ src,
                        const int* __restrict__ dst, const float* __restrict__ ew,
                        int* __restrict__ scanv, int* __restrict__ ssrc,
                        float* __restrict__ sew) {
  int e = blockIdx.x * blockDim.x + threadIdx.x;
  if (e >= E_EDGES) return;
  int bin = et[e] * N_NODES + dst[e];
  int pos = atomicAdd(&scanv[bin], 1);
  ssrc[pos] = src[e];
  sew[pos] = ew[e];
}

// src-only touched nodes -> zero list (block-aggregated reservation)
__global__ void k_zlist(const unsigned char* __restrict__ flag,
                        const int* __restrict__ hist, int* __restrict__ meta,
                        int* __restrict__ zlist) {
  __shared__ int cnt[TSTEPS], base[TSTEPS], cur[TSTEPS];
  int tid = threadIdx.x;
  if (tid < TSTEPS) { cnt[tid] = 0; cur[tid] = 0; }
  __syncthreads();
  int i = blockIdx.x * blockDim.x + tid;
  int t = -1; bool z = false;
  if (i < NBINS) {
    t = i / N_NODES;
    z = flag[i] && (hist[i] == 0);
    if (z) atomicAdd(&cnt[t], 1);
  }
  __syncthreads();
  if (tid < TSTEPS && cnt[tid]) base[tid] = atomicAdd(&meta[40 + tid], cnt[tid]);
  __syncthreads();
  if (z) {
    int p = atomicAdd(&cur[t], 1);
    zlist[(long)t * N_NODES + base[t] + p] = i - t * N_NODES;
  }
}

// ---------------- LSTM part 1: g0 = x@Wih^T + b, g1 = x@(Wih+Whh)^T + b ----------------
__global__ void k_lstm_g(const float* __restrict__ hx, const float* __restrict__ Wih,
                         const float* __restrict__ Whh, const float* __restrict__ bih,
                         const float* __restrict__ bhh, float* __restrict__ g0,
                         float* __restrict__ g1) {
  int i = blockIdx.x >> 9;          // layer
  int c = blockIdx.x & 511;         // gate column 0..511
  int r = threadIdx.x;              // 0..127
  __shared__ float wi[DIM], wh[DIM];
  wi[r] = Wih[((long)i * 4 * DIM + c) * DIM + r];
  wh[r] = Whh[((long)i * 4 * DIM + c) * DIM + r];
  __syncthreads();
  const float* x = hx + ((long)i * DIM + r) * DIM;
  float a = 0.f, b = 0.f;
#pragma unroll 8
  for (int k = 0; k < DIM; ++k) {
    a = fmaf(x[k], wi[k], a);
    b = fmaf(x[k], wh[k], b);
  }
  float base = bih[i * 4 * DIM + c] + bhh[i * 4 * DIM + c];
  long o = ((long)i * 4 * DIM + c) * DIM + r;
  g0[o] = a + base;
  g1[o] = a + b + base;
}

// ---------------- LSTM part 2: gate nonlinearities + select ----------------
__global__ void k_lstm_upd(float* __restrict__ hx, float* __restrict__ cx,
                           const float* __restrict__ g0, const float* __restrict__ g1,
                           const int* __restrict__ meta, int t) {
  int idx = blockIdx.x * blockDim.x + threadIdx.x;
  if (idx >= LLAYERS * DIM * DIM) return;
  int i = idx >> 14;
  int rem = idx & 16383;
  int r = rem >> 7, j = rem & 127;
  long gb = (long)i * 4 * DIM * DIM;
  float gi0 = g0[gb + (0 * DIM + j) * DIM + r];
  float gg0 = g0[gb + (2 * DIM + j) * DIM + r];
  float go0 = g0[gb + (3 * DIM + j) * DIM + r];
  float gi1 = g1[gb + (0 * DIM + j) * DIM + r];
  float gf1 = g1[gb + (1 * DIM + j) * DIM + r];
  float gg1 = g1[gb + (2 * DIM + j) * DIM + r];
  float go1 = g1[gb + (3 * DIM + j) * DIM + r];
  float c_zero = sigm(gi0) * tanhf(gg0);
  float h_zero = sigm(go0) * tanhf(c_zero);
  float c0v = cx[idx];
  float c_st = sigm(gf1) * c0v + sigm(gi1) * tanhf(gg1);
  float h_st = sigm(go1) * tanhf(c_st);
  int first = meta[8 + t];
  int has = meta[t] > 0;
  float hold = hx[idx];
  float hi_v = first ? h_st : h_zero;
  float ci_v = first ? c0v : c_zero;
  hx[idx] = has ? hi_v : hold;
  cx[idx] = has ? ci_v : c0v;
}

// ---------------- weight prep: fp32 [K][128] -> bf16 [kb][c][g-swizzled][8] ----------------
__global__ void k_prep(const float* __restrict__ W, short* __restrict__ Wt, int K) {
  int idx = blockIdx.x * blockDim.x + threadIdx.x;
  int total = (K >> 6) * DIM * 8;
  if (idx >= total) return;
  int g = idx & 7;
  int c = (idx >> 3) & 127;
  int kb = idx >> 10;
  s16x8 s;
#pragma unroll
  for (int j = 0; j < 8; ++j) s[j] = f2bf(W[(long)(kb * 64 + g * 8 + j) * DIM + c]);
  *(s16x8*)&Wt[(((long)kb * DIM + c) * 8 + (g ^ (c & 7))) * 8] = s;
}

// ---------------- segmented scatter: Spack[s] = sum_e w_e * IN[src_e] ----------------
template <bool PACKEDIN>
__global__ void k_segscat(const int* __restrict__ segstart, const int* __restrict__ seglen,
                          const int* __restrict__ ssrc, const float* __restrict__ sew,
                          const float* __restrict__ IN, const int* __restrict__ rowof,
                          float* __restrict__ Spack, const int* __restrict__ nsegp) {
  int nseg = nsegp[0];
  int gsz = gridDim.x * (blockDim.x >> 5);
  int l = threadIdx.x & 31;
  int d4 = l << 2;
  for (int s = blockIdx.x * (blockDim.x >> 5) + (threadIdx.x >> 5); s < nseg; s += gsz) {
    int st = segstart[s], len = seglen[s];
    float4 acc = make_float4(0.f, 0.f, 0.f, 0.f);
    for (int e = st; e < st + len; ++e) {
      float w = sew[e];
      int sn = ssrc[e];
      const float* base;
      if (PACKEDIN) {
        int pr = rowof[sn];
        if (pr < 0) continue;
        base = IN + (long)pr * DIM;
      } else {
        base = IN + (long)sn * DIM;
      }
      const float4 hv = *reinterpret_cast<const float4*>(base + d4);
      acc.x = fmaf(w, hv.x, acc.x);
      acc.y = fmaf(w, hv.y, acc.y);
      acc.z = fmaf(w, hv.z, acc.z);
      acc.w = fmaf(w, hv.w, acc.w);
    }
    *reinterpret_cast<float4*>(Spack + (long)s * DIM + d4) = acc;
  }
}

// ---------------- MFMA GEMM: C[n][c] = act(sum_k A[row(n)][k] * W[k][c] (+bias)) ----
template <int KTILES, bool GATHER, bool RELU, bool BIAS, bool DYN>
__global__ __launch_bounds__(256) void k_gemm_mfma(const float* __restrict__ A,
                                                   const int* __restrict__ rowids,
                                                   const short* __restrict__ Wt,
                                                   const float* __restrict__ bias,
                                                   float* __restrict__ C, int Nc,
                                                   const int* __restrict__ nptr) {
  const int N = DYN ? nptr[0] : Nc;
  const int n0 = blockIdx.x * 128;
  if (n0 >= N) return;
  __shared__ short As[128 * 64];
  __shared__ short Ws[128 * 64];
  __shared__ int rid[128];
  const int tid = threadIdx.x;
  if (GATHER) {
    if (tid < 128) {
      int n = n0 + tid;
      rid[tid] = (n < N) ? rowids[n] * (KTILES * 64) : 0;
    }
  }
  const int lane = tid & 63;
  const int w = tid >> 6;
  f32x4 acc[2][8] = {};
  for (int kt = 0; kt < KTILES; ++kt) {
    __syncthreads();  // rid ready (kt=0) / previous compute done
#pragma unroll
    for (int p = 0; p < 4; ++p) {
      int gi = p * 256 + tid;
      int row = gi >> 3, g = gi & 7;
      int n = n0 + row;
      float4 v0 = make_float4(0.f, 0.f, 0.f, 0.f), v1 = v0;
      if (n < N) {
        long base = GATHER ? (long)rid[row] : (long)n * (KTILES * 64);
        const float* ap = A + base + kt * 64 + g * 8;
        v0 = *reinterpret_cast<const float4*>(ap);
        v1 = *reinterpret_cast<const float4*>(ap + 4);
      }
      s16x8 s;
      s[0] = f2bf(v0.x); s[1] = f2bf(v0.y); s[2] = f2bf(v0.z); s[3] = f2bf(v0.w);
      s[4] = f2bf(v1.x); s[5] = f2bf(v1.y); s[6] = f2bf(v1.z); s[7] = f2bf(v1.w);
      *(s16x8*)&As[(row * 8 + (g ^ (row & 7))) * 8] = s;
    }
    const int4* wg = reinterpret_cast<const int4*>(Wt + kt * 128 * 64);
    int4* wl = reinterpret_cast<int4*>(Ws);
#pragma unroll
    for (int p = 0; p < 4; ++p) wl[p * 256 + tid] = wg[p * 256 + tid];
    __syncthreads();
#pragma unroll
    for (int kk = 0; kk < 2; ++kk) {
      int gb = kk * 4 + (lane >> 4);
      s16x8 a[2];
#pragma unroll
      for (int fr = 0; fr < 2; ++fr) {
        int row = w * 32 + fr * 16 + (lane & 15);
        a[fr] = *(const s16x8*)&As[(row * 8 + (gb ^ (row & 7))) * 8];
      }
#pragma unroll
      for (int fc = 0; fc < 8; ++fc) {
        int col = fc * 16 + (lane & 15);
        s16x8 b = *(const s16x8*)&Ws[(col * 8 + (gb ^ (col & 7))) * 8];
        acc[0][fc] = __builtin_amdgcn_mfma_f32_16x16x32_bf16(a[0], b, acc[0][fc], 0, 0, 0);
        acc[1][fc] = __builtin_amdgcn_mfma_f32_16x16x32_bf16(a[1], b, acc[1][fc], 0, 0, 0);
      }
    }
  }
  // epilogue: C/D layout col=lane&15, row=(lane>>4)*4+reg  [m89-verified]
  const int cb = lane & 15;
  const int rb = w * 32 + (lane >> 4) * 4;
#pragma unroll
  for (int fr = 0; fr < 2; ++fr) {
#pragma unroll
    for (int reg = 0; reg < 4; ++reg) {
      int n = n0 + rb + fr * 16 + reg;
      if (n >= N) continue;
      float* cp = C + (long)n * DIM;
#pragma unroll
      for (int fc = 0; fc < 8; ++fc) {
        float x = acc[fr][fc][reg];
        if (BIAS) x += bias[fc * 16 + cb];
        if (RELU) x = fmaxf(x, 0.f);
        cp[fc * 16 + cb] = x;
      }
    }
  }
}

// ---------------- writeback: h[segdst[s]] = P2[s]; h[zlist[z]] = 0 ----------------
__global__ void k_wb(float* __restrict__ h, const float* __restrict__ P2,
                     const int* __restrict__ segdst, const int* __restrict__ zlist,
                     const int* __restrict__ nsegp, const int* __restrict__ nzp) {
  int nseg = nsegp[0], nz = nzp[0];
  int total = nseg + nz;
  int gsz = gridDim.x * (blockDim.x >> 5);
  int l = threadIdx.x & 31;
  int d4 = l << 2;
  for (int s = blockIdx.x * (blockDim.x >> 5) + (threadIdx.x >> 5); s < total; s += gsz) {
    if (s < nseg) {
      int d = segdst[s];
      *reinterpret_cast<float4*>(h + (long)d * DIM + d4) =
          *reinterpret_cast<const float4*>(P2 + (long)s * DIM + d4);
    } else {
      int n = zlist[s - nseg];
      *reinterpret_cast<float4*>(h + (long)n * DIM + d4) = make_float4(0.f, 0.f, 0.f, 0.f);
    }
  }
}

// ---------------- segment max (graph_id sorted) ----------------
__global__ void k_segmax(const float* __restrict__ h, const int* __restrict__ gid,
                         unsigned* __restrict__ keys) {
  int d = threadIdx.x;  // 0..127
  int n0 = blockIdx.x * 64;
  int end = min(n0 + 64, N_NODES);
  if (n0 >= N_NODES) return;
  int curg = gid[n0];
  float m = -INFINITY;
  for (int n = n0; n < end; ++n) {
    int g = gid[n];
    if (g != curg) {
      atomicMax(&keys[(long)curg * DIM + d], fenc(m));
      curg = g;
      m = -INFINITY;
    }
    m = fmaxf(m, h[(long)n * DIM + d]);
  }
  atomicMax(&keys[(long)curg * DIM + d], fenc(m));
}

// ---------------- final: logits, probs, BCE loss ----------------
__global__ void k_final(const unsigned* __restrict__ keys, const float* __restrict__ outW,
                        const float* __restrict__ outB, const float* __restrict__ y,
                        float* __restrict__ out) {
  __shared__ float lt[BGRAPH];
  int tid = threadIdx.x;  // 64 threads: 4 per graph
  int b = tid >> 2, l4 = tid & 3;
  float s = 0.f;
  for (int d = l4; d < DIM; d += 4) {
    float v = fdec(keys[(long)b * DIM + d]);
    if (!isfinite(v)) v = 0.f;
    s += v * outW[d];
  }
  s += __shfl_down(s, 1);
  s += __shfl_down(s, 2);
  if (l4 == 0) {
    float l = s + outB[0];
    out[1 + b] = 1.f / (1.f + expf(-l));
    lt[b] = fmaxf(l, 0.f) - l * y[b] + log1pf(expf(-fabsf(l)));
  }
  __syncthreads();
  if (tid == 0) {
    float acc = 0.f;
    for (int i = 0; i < BGRAPH; ++i) acc += lt[i];
    out[0] = acc / (float)BGRAPH;
  }
}

extern "C" void kernel_launch(void* const* d_in, const int* in_sizes, int n_in,
                              void* d_out, int out_size, void* d_ws, size_t ws_size,
                              hipStream_t stream) {
  const int* word_ids = (const int*)d_in[0];
  const int* src = (const int*)d_in[1];
  const int* dst = (const int*)d_in[2];
  const int* et = (const int*)d_in[3];
  const float* ew = (const float*)d_in[4];
  const int* gid = (const int*)d_in[5];
  const float* y = (const float*)d_in[6];
  const float* wemb = (const float*)d_in[7];
  const float* adW = (const float*)d_in[8];
  const float* adb = (const float*)d_in[9];
  const float* gcn = (const float*)d_in[10];
  const float* Wih = (const float*)d_in[11];
  const float* Whh = (const float*)d_in[12];
  const float* bih = (const float*)d_in[13];
  const float* bhh = (const float*)d_in[14];
  const float* outW = (const float*)d_in[15];
  const float* outB = (const float*)d_in[16];
  float* out = (float*)d_out;

  char* ws = (char*)d_ws;
  const long ND = (long)N_NODES * DIM;  // 7,680,000 floats
  float* h = (float*)ws;        ws += ND * 4;            // dense node features
  float* P1 = (float*)ws;       ws += ND * 4;            // packed scatter out / GEMM in
  float* P2 = (float*)ws;       ws += ND * 4;            // packed GEMM out
  float* hx = (float*)ws;       ws += LLAYERS * DIM * DIM * 4;
  float* cx = (float*)ws;       ws += LLAYERS * DIM * DIM * 4;
  float* g0 = (float*)ws;       ws += LLAYERS * 4 * DIM * DIM * 4;
  float* g1 = (float*)ws;       ws += LLAYERS * 4 * DIM * DIM * 4;
  int* meta = (int*)ws;         ws += 64 * 4;
  unsigned* keys = (unsigned*)ws; ws += BGRAPH * DIM * 4;
  int* hist = (int*)ws;         ws += (long)NBINS * 4;
  int* scanv = (int*)ws;        ws += (long)NBINS * 4;
  int* scans = (int*)ws;        ws += (long)NBINS * 4;
  int* bsumA = (int*)ws;        ws += ((NB + 63) & ~63) * 4;
  int* bsumB = (int*)ws;        ws += ((NB + 63) & ~63) * 4;
  int* rowof = (int*)ws;        ws += (long)NBINS * 4;
  int* segdst = (int*)ws;       ws += (long)NBINS * 4;
  int* segstart = (int*)ws;     ws += (long)NBINS * 4;
  int* seglen = (int*)ws;       ws += (long)NBINS * 4;
  int* zlist = (int*)ws;        ws += (long)NBINS * 4;
  int* ssrc = (int*)ws;         ws += (long)E_EDGES * 4;
  float* sew = (float*)ws;      ws += (long)E_EDGES * 4;
  unsigned char* flag = (unsigned char*)ws; ws += (NBINS + 63) & ~63;
  short* WtAd = (short*)ws;     ws += 4L * DIM * 64 * 2;
  short* WtL0 = (short*)ws;     ws += 2L * DIM * 64 * 2;
  short* WtL1 = (short*)ws;     ws += 2L * DIM * 64 * 2;

  const int binsblocks = (NBINS + 255) / 256;  // 1407
  const int gemm_blocks = (N_NODES + 127) / 128;

  // setup: sort edges by (t,dst), build segments, rowof, zero-lists — all scan-based
  k_init<<<binsblocks, 256, 0, stream>>>(gcn, hx, cx, meta, keys, hist, rowof, flag);
  k_hist<<<(E_EDGES + 255) / 256, 256, 0, stream>>>(et, src, dst, hist, flag, meta);
  k_scan1b<<<NB, 256, 0, stream>>>(hist, scanv, scans, bsumA, bsumB);
  k_scan2<<<1, 64, 0, stream>>>(bsumA, bsumB, scans, meta);
  k_scan3seg<<<binsblocks, 256, 0, stream>>>(scanv, bsumA, scans, bsumB, hist, meta,
                                             segdst, segstart, seglen, rowof);
  k_place<<<(E_EDGES + 255) / 256, 256, 0, stream>>>(et, src, dst, ew, scanv, ssrc, sew);
  k_zlist<<<binsblocks, 256, 0, stream>>>(flag, hist, meta, zlist);
  k_prep<<<16, 256, 0, stream>>>(adW, WtAd, NINPK);

  // h0 = word_embeds[word_ids] @ adapt_W + adapt_b
  k_gemm_mfma<4, true, false, true, false><<<gemm_blocks, 256, 0, stream>>>(
      wemb, word_ids, WtAd, adb, h, N_NODES, nullptr);

  for (int t = 0; t < TSTEPS; ++t) {
    const int* nsegp = &meta[32 + t];
    const int* nzp = &meta[40 + t];
    const int* ss = segstart + (long)t * N_NODES;
    const int* sl = seglen + (long)t * N_NODES;
    const int* sd = segdst + (long)t * N_NODES;
    const int* ro = rowof + (long)t * N_NODES;
    const int* zl = zlist + (long)t * N_NODES;
    // LSTM weight evolution
    k_lstm_g<<<LLAYERS * 512, 128, 0, stream>>>(hx, Wih, Whh, bih, bhh, g0, g1);
    k_lstm_upd<<<128, 256, 0, stream>>>(hx, cx, g0, g1, meta, t);
    k_prep<<<8, 256, 0, stream>>>(hx, WtL0, DIM);
    k_prep<<<8, 256, 0, stream>>>(hx + DIM * DIM, WtL1, DIM);
    // GCN layer 0: P1 = segscatter(h), P2 = relu(P1 @ hx[0])
    k_segscat<false><<<512, 256, 0, stream>>>(ss, sl, ssrc, sew, h, ro, P1, nsegp);
    k_gemm_mfma<2, false, true, false, true><<<gemm_blocks, 256, 0, stream>>>(
        P1, nullptr, WtL0, nullptr, P2, 0, nsegp);
    // GCN layer 1: P1 = segscatter(P2 via rowof), P2 = relu(P1 @ hx[1])
    k_segscat<true><<<512, 256, 0, stream>>>(ss, sl, ssrc, sew, P2, ro, P1, nsegp);
    k_gemm_mfma<2, false, true, false, true><<<gemm_blocks, 256, 0, stream>>>(
        P1, nullptr, WtL1, nullptr, P2, 0, nsegp);
    // write back: h[dst-rows] = P2 rows; h[src-only touched] = 0
    k_wb<<<256, 256, 0, stream>>>(h, P2, sd, zl, nsegp, nzp);
  }

  k_segmax<<<(N_NODES + 63) / 64, 128, 0, stream>>>(h, gid, keys);
  k_final<<<1, 64, 0, stream>>>(keys, outW, outB, y, out);
}

// Round 6
// 496.859 us; speedup vs baseline: 6.6199x; 1.1534x over previous
//
#include <hip/hip_runtime.h>
#include <hip/hip_bf16.h>
#include <math.h>

#define N_NODES 60000
#define E_EDGES 200000
#define DIM     128
#define NINPK   256
#define TSTEPS  6
#define LLAYERS 2
#define BGRAPH  16
#define NBINS   (TSTEPS * N_NODES)          // 360000
#define NB      ((NBINS + 1023) / 1024)     // 352 scan blocks

typedef float f32x4 __attribute__((ext_vector_type(4)));
typedef short s16x8 __attribute__((ext_vector_type(8)));
typedef short s16x4 __attribute__((ext_vector_type(4)));

static __device__ __forceinline__ float sigm(float x) { return 1.f / (1.f + expf(-x)); }

// round-to-nearest-even float -> bf16 bits
static __device__ __forceinline__ short f2bf(float f) {
  unsigned u = __float_as_uint(f);
  u += 0x7FFFu + ((u >> 16) & 1u);
  return (short)(u >> 16);
}
static __device__ __forceinline__ float bf2f(short s) {
  return __uint_as_float(((unsigned)(unsigned short)s) << 16);
}

// order-preserving float <-> uint for atomicMax-based segment max
static __device__ __forceinline__ unsigned fenc(float f) {
  unsigned u = __float_as_uint(f);
  return (u & 0x80000000u) ? ~u : (u | 0x80000000u);
}
static __device__ __forceinline__ float fdec(unsigned u) {
  u = (u & 0x80000000u) ? (u & 0x7fffffffu) : ~u;
  return __uint_as_float(u);
}

// P1b element (row, d): granule g=d>>3 stored at ((g&8) | ((g&7)^(row&7)))
// => GEMM A-staging for k-tile kt is a LINEAR 16B copy of P1b[row][kt*64 .. +64).

// meta: [0..5]=edge cnt/t [8..13]=first [32..37]=segcnt [40..45]=zcnt [48..53]=rank base
// ---------------- init ----------------
__global__ void k_init(const float* __restrict__ gcn, float* __restrict__ hx0,
                       float* __restrict__ cx, int* __restrict__ meta,
                       unsigned* __restrict__ keys, int* __restrict__ hist,
                       int* __restrict__ rowof, unsigned char* __restrict__ flag) {
  int i = blockIdx.x * blockDim.x + threadIdx.x;
  if (i < LLAYERS * DIM * DIM) { hx0[i] = gcn[i]; cx[i] = 0.f; }
  if (i < BGRAPH * DIM) keys[i] = 0u;
  if (i < 64) meta[i] = 0;
  if (i < NBINS) { hist[i] = 0; rowof[i] = -1; flag[i] = 0; }
}

// ---------------- histogram by (t,dst); src flags; per-t edge counts ----------------
__global__ void k_hist(const int* __restrict__ et, const int* __restrict__ src,
                       const int* __restrict__ dst, int* __restrict__ hist,
                       unsigned char* __restrict__ flag, int* __restrict__ meta) {
  __shared__ int loc[TSTEPS];
  int tid = threadIdx.x;
  if (tid < TSTEPS) loc[tid] = 0;
  __syncthreads();
  int e = blockIdx.x * blockDim.x + tid;
  if (e < E_EDGES) {
    int t = et[e];
    atomicAdd(&hist[t * N_NODES + dst[e]], 1);
    flag[t * N_NODES + src[e]] = 1;
    atomicAdd(&loc[t], 1);
  }
  __syncthreads();
  if (tid < TSTEPS && loc[tid]) atomicAdd(&meta[tid], loc[tid]);
}

// ---------------- fused 2-level exclusive scan: hist values AND nonempty indicator ----
__global__ void k_scan1b(const int* __restrict__ hist, int* __restrict__ scanv,
                         int* __restrict__ scans, int* __restrict__ bsumA,
                         int* __restrict__ bsumB) {
  __shared__ int shA[256], shB[256];
  int b0 = blockIdx.x * 1024;
  int tid = threadIdx.x;
  int v[4], w[4]; int sA = 0, sB = 0;
#pragma unroll
  for (int q = 0; q < 4; ++q) {
    int i = b0 + tid * 4 + q;
    int c = (i < NBINS) ? hist[i] : 0;
    v[q] = c; w[q] = (c > 0) ? 1 : 0;
    sA += c; sB += w[q];
  }
  shA[tid] = sA; shB[tid] = sB;
  __syncthreads();
  for (int off = 1; off < 256; off <<= 1) {
    int xA = (tid >= off) ? shA[tid - off] : 0;
    int xB = (tid >= off) ? shB[tid - off] : 0;
    __syncthreads();
    shA[tid] += xA; shB[tid] += xB;
    __syncthreads();
  }
  int exA = shA[tid] - sA, exB = shB[tid] - sB;
#pragma unroll
  for (int q = 0; q < 4; ++q) {
    int i = b0 + tid * 4 + q;
    if (i < NBINS) { scanv[i] = exA; scans[i] = exB; }
    exA += v[q]; exB += w[q];
  }
  if (tid == 255) { bsumA[blockIdx.x] = shA[255]; bsumB[blockIdx.x] = shB[255]; }
}

__global__ void k_scan2(int* __restrict__ bsumA, int* __restrict__ bsumB,
                        const int* __restrict__ scans, int* __restrict__ meta) {
  if (blockIdx.x == 0 && threadIdx.x == 0) {
    int sA = 0, sB = 0;
    for (int i = 0; i < NB; ++i) {
      int a = bsumA[i]; bsumA[i] = sA; sA += a;
      int b = bsumB[i]; bsumB[i] = sB; sB += b;
    }
    int f = 0;
    for (int t = 0; t < TSTEPS; ++t) { meta[8 + t] = f; f |= (meta[t] > 0); }
    for (int t = 0; t < TSTEPS; ++t) {
      int lo = scans[t * N_NODES] + bsumB[(t * N_NODES) >> 10];
      int hi = (t == TSTEPS - 1)
                   ? sB
                   : scans[(t + 1) * N_NODES] + bsumB[((t + 1) * N_NODES) >> 10];
      meta[32 + t] = hi - lo;   // segment count
      meta[48 + t] = lo;        // rank base
    }
  }
}

// finalize edge-offset scan; build segments via scan ranks (NO atomics)
__global__ void k_scan3seg(int* __restrict__ scanv, const int* __restrict__ bsumA,
                           const int* __restrict__ scans, const int* __restrict__ bsumB,
                           const int* __restrict__ hist, const int* __restrict__ meta,
                           int* __restrict__ segdst, int* __restrict__ segstart,
                           int* __restrict__ seglen, int* __restrict__ rowof) {
  int i = blockIdx.x * blockDim.x + threadIdx.x;
  if (i >= NBINS) return;
  int vA = scanv[i] + bsumA[i >> 10];
  scanv[i] = vA;
  int c = hist[i];
  if (c > 0) {
    int t = i / N_NODES;
    int tb = t * N_NODES;
    int sidx = scans[i] + bsumB[i >> 10] - meta[48 + t];
    long sb = (long)tb + sidx;
    segdst[sb] = i - tb;
    segstart[sb] = vA;
    seglen[sb] = c;
    rowof[i] = sidx;
  }
}

// place edges into sorted order (scanv used as destructive cursor)
__global__ void k_place(const int* __restrict__ et, const int* __restrict__ src,
                        const int* __restrict__ dst, const float* __restrict__ ew,
                        int* __restrict__ scanv, int* __restrict__ ssrc,
                        float* __restrict__ sew) {
  int e = blockIdx.x * blockDim.x + threadIdx.x;
  if (e >= E_EDGES) return;
  int bin = et[e] * N_NODES + dst[e];
  int pos = atomicAdd(&scanv[bin], 1);
  ssrc[pos] = src[e];
  sew[pos] = ew[e];
}

// src-only touched nodes -> zero list (block-aggregated reservation)
__global__ void k_zlist(const unsigned char* __restrict__ flag,
                        const int* __restrict__ hist, int* __restrict__ meta,
                        int* __restrict__ zlist) {
  __shared__ int cnt[TSTEPS], base[TSTEPS], cur[TSTEPS];
  int tid = threadIdx.x;
  if (tid < TSTEPS) { cnt[tid] = 0; cur[tid] = 0; }
  __syncthreads();
  int i = blockIdx.x * blockDim.x + tid;
  int t = -1; bool z = false;
  if (i < NBINS) {
    t = i / N_NODES;
    z = flag[i] && (hist[i] == 0);
    if (z) atomicAdd(&cnt[t], 1);
  }
  __syncthreads();
  if (tid < TSTEPS && cnt[tid]) base[tid] = atomicAdd(&meta[40 + tid], cnt[tid]);
  __syncthreads();
  if (z) {
    int p = atomicAdd(&cur[t], 1);
    zlist[(long)t * N_NODES + base[t] + p] = i - t * N_NODES;
  }
}

// ---------------- fused LSTM: gates + nonlinearities + hx/cx update + bf16 Wt ------
// block = (layer i, out-col j), threads r = batch row. hx ping-pong (hxc -> hxn).
__global__ __launch_bounds__(128) void k_lstm(
    const float* __restrict__ hxc, float* __restrict__ hxn, float* __restrict__ cx,
    const float* __restrict__ Wih, const float* __restrict__ Whh,
    const float* __restrict__ bih, const float* __restrict__ bhh,
    const int* __restrict__ meta, short* __restrict__ WtL0,
    short* __restrict__ WtL1, int t) {
  int i = blockIdx.x >> 7;
  int j = blockIdx.x & 127;
  int r = threadIdx.x;
  __shared__ float wi[4][DIM], wh[4][DIM];
#pragma unroll
  for (int g4 = 0; g4 < 4; ++g4) {
    wi[g4][r] = Wih[((long)i * 512 + g4 * 128 + j) * DIM + r];
    wh[g4][r] = Whh[((long)i * 512 + g4 * 128 + j) * DIM + r];
  }
  __syncthreads();
  const float4* x4 = reinterpret_cast<const float4*>(hxc + ((long)i * DIM + r) * DIM);
  float a0 = 0, a1 = 0, a2 = 0, a3 = 0, b0 = 0, b1 = 0, b2 = 0, b3 = 0;
#pragma unroll 4
  for (int k4 = 0; k4 < 32; ++k4) {
    float4 xv = x4[k4];
    const float* vp = &xv.x;
#pragma unroll
    for (int q = 0; q < 4; ++q) {
      int k = k4 * 4 + q;
      float xs = vp[q];
      a0 = fmaf(xs, wi[0][k], a0); a1 = fmaf(xs, wi[1][k], a1);
      a2 = fmaf(xs, wi[2][k], a2); a3 = fmaf(xs, wi[3][k], a3);
      b0 = fmaf(xs, wh[0][k], b0); b1 = fmaf(xs, wh[1][k], b1);
      b2 = fmaf(xs, wh[2][k], b2); b3 = fmaf(xs, wh[3][k], b3);
    }
  }
  int cb = i * 512 + j;
  float bs0 = bih[cb] + bhh[cb];
  float bs1 = bih[cb + 128] + bhh[cb + 128];
  float bs2 = bih[cb + 256] + bhh[cb + 256];
  float bs3 = bih[cb + 384] + bhh[cb + 384];
  float g0i = a0 + bs0, g0f = a1 + bs1, g0g = a2 + bs2, g0o = a3 + bs3;
  float g1i = g0i + b0, g1f = g0f + b1, g1g = g0g + b2, g1o = g0o + b3;
  int idx = i * 16384 + r * 128 + j;
  float c0v = cx[idx];
  float c_zero = sigm(g0i) * tanhf(g0g);
  float h_zero = sigm(g0o) * tanhf(c_zero);
  float c_st = sigm(g1f) * c0v + sigm(g1i) * tanhf(g1g);
  float h_st = sigm(g1o) * tanhf(c_st);
  int first = meta[8 + t];
  int has = meta[t] > 0;
  float hi_v = first ? h_st : h_zero;
  float ci_v = first ? c0v : c_zero;
  // hold value = hx_old[i][r][j] = x[j]
  float xj = reinterpret_cast<const float*>(x4)[j];
  float hnew = has ? hi_v : xj;
  float cnew = has ? ci_v : c0v;
  hxn[idx] = hnew;
  cx[idx] = cnew;
  // bf16 weight tile: W[k=r][c=j], granule layout matching GEMM Ws
  short* Wt = i ? WtL1 : WtL0;
  int kb = r >> 6, g = (r >> 3) & 7, jj = r & 7;
  Wt[((kb * DIM + j) * 8 + (g ^ (j & 7))) * 8 + jj] = f2bf(hnew);
}

// ---------------- weight prep (adapt): fp32 [K][128] -> bf16 granule layout -------
__global__ void k_prep(const float* __restrict__ W, short* __restrict__ Wt, int K) {
  int idx = blockIdx.x * blockDim.x + threadIdx.x;
  int total = (K >> 6) * DIM * 8;
  if (idx >= total) return;
  int g = idx & 7;
  int c = (idx >> 3) & 127;
  int kb = idx >> 10;
  s16x8 s;
#pragma unroll
  for (int j = 0; j < 8; ++j) s[j] = f2bf(W[(long)(kb * 64 + g * 8 + j) * DIM + c]);
  *(s16x8*)&Wt[(((long)kb * DIM + c) * 8 + (g ^ (c & 7))) * 8] = s;
}

// ---------------- wemb fp32 -> bf16 linear ----------------
__global__ void k_prepw(const float* __restrict__ in, short* __restrict__ out, long n8) {
  long i = (long)blockIdx.x * blockDim.x + threadIdx.x;
  if (i >= n8) return;
  const float4* p = reinterpret_cast<const float4*>(in + i * 8);
  float4 v0 = p[0], v1 = p[1];
  s16x8 s;
  s[0] = f2bf(v0.x); s[1] = f2bf(v0.y); s[2] = f2bf(v0.z); s[3] = f2bf(v0.w);
  s[4] = f2bf(v1.x); s[5] = f2bf(v1.y); s[6] = f2bf(v1.z); s[7] = f2bf(v1.w);
  *(s16x8*)&out[i * 8] = s;
}

// ---------------- segmented scatter: P1b[s] = bf16(sum_e w_e * IN[src_e]) ----------
// IN is bf16; acc fp32; output pre-swizzled for GEMM A-staging. No atomics.
template <bool PACKEDIN>
__global__ void k_segscat(const int* __restrict__ segstart, const int* __restrict__ seglen,
                          const int* __restrict__ ssrc, const float* __restrict__ sew,
                          const short* __restrict__ IN16, const int* __restrict__ rowof,
                          short* __restrict__ P1b, const int* __restrict__ nsegp) {
  int nseg = nsegp[0];
  int gsz = gridDim.x * (blockDim.x >> 5);
  int l = threadIdx.x & 31;
  int d4 = l << 2;
  int g = l >> 1, j0 = (l & 1) * 4;
  for (int s = blockIdx.x * (blockDim.x >> 5) + (threadIdx.x >> 5); s < nseg; s += gsz) {
    int st = segstart[s], len = seglen[s];
    float acc0 = 0.f, acc1 = 0.f, acc2 = 0.f, acc3 = 0.f;
    for (int e = st; e < st + len; ++e) {
      float w = sew[e];
      int sn = ssrc[e];
      long rbase;
      if (PACKEDIN) {
        int pr = rowof[sn];
        if (pr < 0) continue;
        rbase = (long)pr * DIM;
      } else {
        rbase = (long)sn * DIM;
      }
      s16x4 hv = *reinterpret_cast<const s16x4*>(&IN16[rbase + d4]);
      acc0 = fmaf(w, bf2f(hv[0]), acc0);
      acc1 = fmaf(w, bf2f(hv[1]), acc1);
      acc2 = fmaf(w, bf2f(hv[2]), acc2);
      acc3 = fmaf(w, bf2f(hv[3]), acc3);
    }
    s16x4 pk;
    pk[0] = f2bf(acc0); pk[1] = f2bf(acc1); pk[2] = f2bf(acc2); pk[3] = f2bf(acc3);
    long off = (long)s * DIM + (((g & 8) | ((g & 7) ^ (s & 7))) * 8) + j0;
    *reinterpret_cast<s16x4*>(&P1b[off]) = pk;
  }
}

// ---------------- MFMA GEMM: C16[row(n)] = act(A16[n] @ Wt (+bias)) ----------------
// A16: bf16, pre-swizzled (direct) or linear rows (GATHER). C16: bf16 linear or
// gathered via dstmap (GOUT).
template <int KTILES, bool GATHER, bool RELU, bool BIAS, bool DYN, bool GOUT>
__global__ __launch_bounds__(256) void k_gemm_mfma(const short* __restrict__ A16,
                                                   const int* __restrict__ rowids,
                                                   const short* __restrict__ Wt,
                                                   const float* __restrict__ bias,
                                                   short* __restrict__ C16,
                                                   const int* __restrict__ dstmap,
                                                   int Nc, const int* __restrict__ nptr) {
  __shared__ short As[128 * 64];
  __shared__ short Ws[128 * 64];
  __shared__ int rid[128];
  const int N = DYN ? nptr[0] : Nc;
  const int n0 = blockIdx.x * 128;
  if (n0 >= N) return;
  const int tid = threadIdx.x;
  if (GATHER) {
    if (tid < 128) {
      int n = n0 + tid;
      rid[tid] = (n < N) ? rowids[n] * (KTILES * 64) : 0;
    }
  }
  const int lane = tid & 63;
  const int w = tid >> 6;
  f32x4 acc[2][8] = {};
  for (int kt = 0; kt < KTILES; ++kt) {
    __syncthreads();  // rid ready (kt=0) / previous compute done
#pragma unroll
    for (int p = 0; p < 4; ++p) {
      int gi = p * 256 + tid;
      int row = gi >> 3, s = gi & 7;
      int n = n0 + row;
      s16x8 v = {};
      if (n < N) {
        if (GATHER) {
          // linear source rows; swizzle applied via source granule index
          v = *(const s16x8*)&A16[(long)rid[row] + kt * 64 + (s ^ (row & 7)) * 8];
        } else {
          // P1b is pre-swizzled: straight copy
          v = *(const s16x8*)&A16[(long)n * (KTILES * 64) + kt * 64 + s * 8];
        }
      }
      *(s16x8*)&As[(row * 8 + s) * 8] = v;
    }
    const int4* wg = reinterpret_cast<const int4*>(Wt + kt * 128 * 64);
    int4* wl = reinterpret_cast<int4*>(Ws);
#pragma unroll
    for (int p = 0; p < 4; ++p) wl[p * 256 + tid] = wg[p * 256 + tid];
    __syncthreads();
#pragma unroll
    for (int kk = 0; kk < 2; ++kk) {
      int gb = kk * 4 + (lane >> 4);
      s16x8 a[2];
#pragma unroll
      for (int fr = 0; fr < 2; ++fr) {
        int row = w * 32 + fr * 16 + (lane & 15);
        a[fr] = *(const s16x8*)&As[(row * 8 + (gb ^ (row & 7))) * 8];
      }
#pragma unroll
      for (int fc = 0; fc < 8; ++fc) {
        int col = fc * 16 + (lane & 15);
        s16x8 b = *(const s16x8*)&Ws[(col * 8 + (gb ^ (col & 7))) * 8];
        acc[0][fc] = __builtin_amdgcn_mfma_f32_16x16x32_bf16(a[0], b, acc[0][fc], 0, 0, 0);
        acc[1][fc] = __builtin_amdgcn_mfma_f32_16x16x32_bf16(a[1], b, acc[1][fc], 0, 0, 0);
      }
    }
  }
  // epilogue: C/D layout col=lane&15, row=(lane>>4)*4+reg  [m89-verified]
  const int cb = lane & 15;
  const int rb = w * 32 + (lane >> 4) * 4;
#pragma unroll
  for (int fr = 0; fr < 2; ++fr) {
#pragma unroll
    for (int reg = 0; reg < 4; ++reg) {
      int n = n0 + rb + fr * 16 + reg;
      if (n >= N) continue;
      long drow = GOUT ? (long)dstmap[n] : (long)n;
      short* cp = C16 + drow * DIM;
#pragma unroll
      for (int fc = 0; fc < 8; ++fc) {
        float x = acc[fr][fc][reg];
        if (BIAS) x += bias[fc * 16 + cb];
        if (RELU) x = fmaxf(x, 0.f);
        cp[fc * 16 + cb] = f2bf(x);
      }
    }
  }
}

// ---------------- zero src-only touched rows of hb ----------------
__global__ void k_zzero(short* __restrict__ hb, const int* __restrict__ zlist,
                        const int* __restrict__ nzp) {
  int nz = nzp[0];
  int gsz = gridDim.x * (blockDim.x >> 5);
  int l = threadIdx.x & 31;
  s16x4 z = {};
  for (int s = blockIdx.x * (blockDim.x >> 5) + (threadIdx.x >> 5); s < nz; s += gsz) {
    int n = zlist[s];
    *reinterpret_cast<s16x4*>(&hb[(long)n * DIM + l * 4]) = z;
  }
}

// ---------------- segment max (graph_id sorted), bf16 input ----------------
__global__ void k_segmax(const short* __restrict__ hb, const int* __restrict__ gid,
                         unsigned* __restrict__ keys) {
  int d = threadIdx.x;  // 0..127
  int n0 = blockIdx.x * 64;
  int end = min(n0 + 64, N_NODES);
  if (n0 >= N_NODES) return;
  int curg = gid[n0];
  float m = -INFINITY;
  for (int n = n0; n < end; ++n) {
    int g = gid[n];
    if (g != curg) {
      atomicMax(&keys[(long)curg * DIM + d], fenc(m));
      curg = g;
      m = -INFINITY;
    }
    m = fmaxf(m, bf2f(hb[(long)n * DIM + d]));
  }
  atomicMax(&keys[(long)curg * DIM + d], fenc(m));
}

// ---------------- final: logits, probs, BCE loss ----------------
__global__ void k_final(const unsigned* __restrict__ keys, const float* __restrict__ outW,
                        const float* __restrict__ outB, const float* __restrict__ y,
                        float* __restrict__ out) {
  __shared__ float lt[BGRAPH];
  int tid = threadIdx.x;  // 64 threads: 4 per graph
  int b = tid >> 2, l4 = tid & 3;
  float s = 0.f;
  for (int d = l4; d < DIM; d += 4) {
    float v = fdec(keys[(long)b * DIM + d]);
    if (!isfinite(v)) v = 0.f;
    s += v * outW[d];
  }
  s += __shfl_down(s, 1);
  s += __shfl_down(s, 2);
  if (l4 == 0) {
    float l = s + outB[0];
    out[1 + b] = 1.f / (1.f + expf(-l));
    lt[b] = fmaxf(l, 0.f) - l * y[b] + log1pf(expf(-fabsf(l)));
  }
  __syncthreads();
  if (tid == 0) {
    float acc = 0.f;
    for (int i = 0; i < BGRAPH; ++i) acc += lt[i];
    out[0] = acc / (float)BGRAPH;
  }
}

extern "C" void kernel_launch(void* const* d_in, const int* in_sizes, int n_in,
                              void* d_out, int out_size, void* d_ws, size_t ws_size,
                              hipStream_t stream) {
  const int* word_ids = (const int*)d_in[0];
  const int* src = (const int*)d_in[1];
  const int* dst = (const int*)d_in[2];
  const int* et = (const int*)d_in[3];
  const float* ew = (const float*)d_in[4];
  const int* gid = (const int*)d_in[5];
  const float* y = (const float*)d_in[6];
  const float* wemb = (const float*)d_in[7];
  const float* adW = (const float*)d_in[8];
  const float* adb = (const float*)d_in[9];
  const float* gcn = (const float*)d_in[10];
  const float* Wih = (const float*)d_in[11];
  const float* Whh = (const float*)d_in[12];
  const float* bih = (const float*)d_in[13];
  const float* bhh = (const float*)d_in[14];
  const float* outW = (const float*)d_in[15];
  const float* outB = (const float*)d_in[16];
  float* out = (float*)d_out;

  char* ws = (char*)d_ws;
  const long ND = (long)N_NODES * DIM;
  short* hb = (short*)ws;       ws += ND * 2;            // bf16 node features
  short* P1b = (short*)ws;      ws += ND * 2;            // bf16 packed, pre-swizzled
  short* P2b = (short*)ws;      ws += ND * 2;            // bf16 packed, linear
  float* hxA = (float*)ws;      ws += LLAYERS * DIM * DIM * 4;
  float* hxB = (float*)ws;      ws += LLAYERS * DIM * DIM * 4;
  float* cx = (float*)ws;       ws += LLAYERS * DIM * DIM * 4;
  int* meta = (int*)ws;         ws += 64 * 4;
  unsigned* keys = (unsigned*)ws; ws += BGRAPH * DIM * 4;
  int* hist = (int*)ws;         ws += (long)NBINS * 4;
  int* scanv = (int*)ws;        ws += (long)NBINS * 4;
  int* scans = (int*)ws;        ws += (long)NBINS * 4;
  int* bsumA = (int*)ws;        ws += ((NB + 63) & ~63) * 4;
  int* bsumB = (int*)ws;        ws += ((NB + 63) & ~63) * 4;
  int* rowof = (int*)ws;        ws += (long)NBINS * 4;
  int* segdst = (int*)ws;       ws += (long)NBINS * 4;
  int* segstart = (int*)ws;     ws += (long)NBINS * 4;
  int* seglen = (int*)ws;       ws += (long)NBINS * 4;
  int* zlist = (int*)ws;        ws += (long)NBINS * 4;
  int* ssrc = (int*)ws;         ws += (long)E_EDGES * 4;
  float* sew = (float*)ws;      ws += (long)E_EDGES * 4;
  short* wembb = (short*)ws;    ws += 15000L * NINPK * 2;  // 7.68 MB
  short* WtAd = (short*)ws;     ws += 4L * DIM * 64 * 2;
  short* WtL0 = (short*)ws;     ws += 2L * DIM * 64 * 2;
  short* WtL1 = (short*)ws;     ws += 2L * DIM * 64 * 2;
  unsigned char* flag = (unsigned char*)ws; ws += (NBINS + 63) & ~63;

  const int binsblocks = (NBINS + 255) / 256;
  const int gemm_blocks = (N_NODES + 127) / 128;

  // setup: sort edges by (t,dst), segments, rowof, zero-lists — scan-based
  k_init<<<binsblocks, 256, 0, stream>>>(gcn, hxA, cx, meta, keys, hist, rowof, flag);
  k_hist<<<(E_EDGES + 255) / 256, 256, 0, stream>>>(et, src, dst, hist, flag, meta);
  k_scan1b<<<NB, 256, 0, stream>>>(hist, scanv, scans, bsumA, bsumB);
  k_scan2<<<1, 64, 0, stream>>>(bsumA, bsumB, scans, meta);
  k_scan3seg<<<binsblocks, 256, 0, stream>>>(scanv, bsumA, scans, bsumB, hist, meta,
                                             segdst, segstart, seglen, rowof);
  k_place<<<(E_EDGES + 255) / 256, 256, 0, stream>>>(et, src, dst, ew, scanv, ssrc, sew);
  k_zlist<<<binsblocks, 256, 0, stream>>>(flag, hist, meta, zlist);
  k_prepw<<<(int)((15000L * NINPK / 8 + 255) / 256), 256, 0, stream>>>(
      wemb, wembb, 15000L * NINPK / 8);
  k_prep<<<16, 256, 0, stream>>>(adW, WtAd, NINPK);

  // hb = bf16(word_embeds[word_ids] @ adapt_W + adapt_b)
  k_gemm_mfma<4, true, false, true, false, false><<<gemm_blocks, 256, 0, stream>>>(
      wembb, word_ids, WtAd, adb, hb, nullptr, N_NODES, nullptr);

  for (int t = 0; t < TSTEPS; ++t) {
    const int* nsegp = &meta[32 + t];
    const int* nzp = &meta[40 + t];
    const int* ss = segstart + (long)t * N_NODES;
    const int* sl = seglen + (long)t * N_NODES;
    const int* sd = segdst + (long)t * N_NODES;
    const int* ro = rowof + (long)t * N_NODES;
    const int* zl = zlist + (long)t * N_NODES;
    const float* hxc = (t & 1) ? hxB : hxA;
    float* hxn = (t & 1) ? hxA : hxB;
    // fused LSTM weight evolution (+ bf16 weight tiles)
    k_lstm<<<LLAYERS * DIM, 128, 0, stream>>>(hxc, hxn, cx, Wih, Whh, bih, bhh,
                                              meta, WtL0, WtL1, t);
    // GCN layer 0: P1b = segscatter(hb) [reads hb BEFORE any write this step]
    k_segscat<false><<<512, 256, 0, stream>>>(ss, sl, ssrc, sew, hb, ro, P1b, nsegp);
    // zero src-only touched rows (disjoint from dst rows; hb reads done)
    k_zzero<<<256, 256, 0, stream>>>(hb, zl, nzp);
    // P2b = relu(P1b @ W0)
    k_gemm_mfma<2, false, true, false, true, false><<<gemm_blocks, 256, 0, stream>>>(
        P1b, nullptr, WtL0, nullptr, P2b, nullptr, 0, nsegp);
    // GCN layer 1: P1b = segscatter(P2b via rowof); hb[segdst] = relu(P1b @ W1)
    k_segscat<true><<<512, 256, 0, stream>>>(ss, sl, ssrc, sew, P2b, ro, P1b, nsegp);
    k_gemm_mfma<2, false, true, false, true, true><<<gemm_blocks, 256, 0, stream>>>(
        P1b, nullptr, WtL1, nullptr, hb, sd, 0, nsegp);
  }

  k_segmax<<<(N_NODES + 63) / 64, 128, 0, stream>>>(hb, gid, keys);
  k_final<<<1, 64, 0, stream>>>(keys, outW, outB, y, out);
}

// Round 7
// 409.621 us; speedup vs baseline: 8.0297x; 1.2130x over previous
//
#include <hip/hip_runtime.h>
#include <hip/hip_bf16.h>
#include <math.h>

#define N_NODES 60000
#define E_EDGES 200000
#define DIM     128
#define NINPK   256
#define TSTEPS  6
#define LLAYERS 2
#define BGRAPH  16
#define NBINS   (TSTEPS * N_NODES)          // 360000
#define NB      ((NBINS + 1023) / 1024)     // 352 scan blocks
#define NWORDS  15000

#define B_INITP  ((NBINS + 255) / 256)          // 1407
#define B_PREPW  (NWORDS * NINPK / 8 / 256)     // 1875
#define B_PREP   16
#define B_PLACE  ((E_EDGES + 255) / 256)        // 782
#define B_TGEMM  ((NWORDS + 127) / 128)         // 118
#define GB       ((N_NODES + 127) / 128)        // 469 gemm blocks (dyn early-exit)
#define B_SCAT   512
#define B_LSTM   128
#define B_ZZ     64

typedef float f32x4 __attribute__((ext_vector_type(4)));
typedef short s16x8 __attribute__((ext_vector_type(8)));
typedef short s16x4 __attribute__((ext_vector_type(4)));

static __device__ __forceinline__ float sigm(float x) { return 1.f / (1.f + expf(-x)); }

static __device__ __forceinline__ short f2bf(float f) {
  unsigned u = __float_as_uint(f);
  u += 0x7FFFu + ((u >> 16) & 1u);
  return (short)(u >> 16);
}
static __device__ __forceinline__ float bf2f(short s) {
  return __uint_as_float(((unsigned)(unsigned short)s) << 16);
}
static __device__ __forceinline__ unsigned fenc(float f) {
  unsigned u = __float_as_uint(f);
  return (u & 0x80000000u) ? ~u : (u | 0x80000000u);
}
static __device__ __forceinline__ float fdec(unsigned u) {
  u = (u & 0x80000000u) ? (u & 0x7fffffffu) : ~u;
  return __uint_as_float(u);
}

// ============ device bodies ============

// GEMM: C16[row] = act(A16 @ Wt (+bias)). MODE 0: A pre-swizzled; MODE 2: linear rows.
template <int KTILES, int MODE, bool RELU, bool BIAS, bool DYN, bool GOUT>
static __device__ __forceinline__ void gemm_body(
    const short* __restrict__ A16, const short* __restrict__ Wt,
    const float* __restrict__ bias, short* __restrict__ C16,
    const int* __restrict__ dstmap, int Nc, const int* __restrict__ nptr,
    short* As, short* Ws, int bid) {
  const int N = DYN ? nptr[0] : Nc;
  const int n0 = bid * 128;
  if (n0 >= N) return;
  const int tid = threadIdx.x;
  const int lane = tid & 63;
  const int w = tid >> 6;
  f32x4 acc[2][8] = {};
  for (int kt = 0; kt < KTILES; ++kt) {
    __syncthreads();
#pragma unroll
    for (int p = 0; p < 4; ++p) {
      int gi = p * 256 + tid;
      int row = gi >> 3, s = gi & 7;
      int n = n0 + row;
      s16x8 v = {};
      if (n < N) {
        if (MODE == 0) {
          v = *(const s16x8*)&A16[(long)n * (KTILES * 64) + kt * 64 + s * 8];
        } else {
          v = *(const s16x8*)&A16[(long)n * (KTILES * 64) + kt * 64 + (s ^ (row & 7)) * 8];
        }
      }
      *(s16x8*)&As[(row * 8 + s) * 8] = v;
    }
    const int4* wg = reinterpret_cast<const int4*>(Wt + kt * 128 * 64);
    int4* wl = reinterpret_cast<int4*>(Ws);
#pragma unroll
    for (int p = 0; p < 4; ++p) wl[p * 256 + tid] = wg[p * 256 + tid];
    __syncthreads();
#pragma unroll
    for (int kk = 0; kk < 2; ++kk) {
      int gb = kk * 4 + (lane >> 4);
      s16x8 a[2];
#pragma unroll
      for (int fr = 0; fr < 2; ++fr) {
        int row = w * 32 + fr * 16 + (lane & 15);
        a[fr] = *(const s16x8*)&As[(row * 8 + (gb ^ (row & 7))) * 8];
      }
#pragma unroll
      for (int fc = 0; fc < 8; ++fc) {
        int col = fc * 16 + (lane & 15);
        s16x8 b = *(const s16x8*)&Ws[(col * 8 + (gb ^ (col & 7))) * 8];
        acc[0][fc] = __builtin_amdgcn_mfma_f32_16x16x32_bf16(a[0], b, acc[0][fc], 0, 0, 0);
        acc[1][fc] = __builtin_amdgcn_mfma_f32_16x16x32_bf16(a[1], b, acc[1][fc], 0, 0, 0);
      }
    }
  }
  // epilogue: C/D layout col=lane&15, row=(lane>>4)*4+reg  [m89-verified]
  const int cb = lane & 15;
  const int rb = w * 32 + (lane >> 4) * 4;
#pragma unroll
  for (int fr = 0; fr < 2; ++fr) {
#pragma unroll
    for (int reg = 0; reg < 4; ++reg) {
      int n = n0 + rb + fr * 16 + reg;
      if (n >= N) continue;
      long drow = GOUT ? (long)dstmap[n] : (long)n;
      short* cp = C16 + drow * DIM;
#pragma unroll
      for (int fc = 0; fc < 8; ++fc) {
        float x = acc[fr][fc][reg];
        if (BIAS) x += bias[fc * 16 + cb];
        if (RELU) x = fmaxf(x, 0.f);
        cp[fc * 16 + cb] = f2bf(x);
      }
    }
  }
}

// segmented scatter: P1b[s] (pre-swizzled) = bf16(sum_e w_e * IN16[rowof_e])
// sedge: {row_or_node, w_bits}; PACKEDIN rows may be -1 (skip).
template <bool PACKEDIN>
static __device__ __forceinline__ void segscat_body(
    const int* __restrict__ segstart, const int* __restrict__ seglen,
    const int2* __restrict__ sedge, const short* __restrict__ IN16,
    short* __restrict__ P1b, int nseg, int bid, int nblocks) {
  int gsz = nblocks * 8;
  int l = threadIdx.x & 31;
  int d4 = l << 2;
  int g = l >> 1, j0 = (l & 1) * 4;
  for (int s = bid * 8 + (threadIdx.x >> 5); s < nseg; s += gsz) {
    int st = segstart[s], len = seglen[s];
    float acc0 = 0.f, acc1 = 0.f, acc2 = 0.f, acc3 = 0.f;
    for (int e = st; e < st + len; ++e) {
      int2 v = sedge[e];
      if (PACKEDIN && v.x < 0) continue;
      float w = __int_as_float(v.y);
      s16x4 hv = *reinterpret_cast<const s16x4*>(&IN16[(long)v.x * DIM + d4]);
      acc0 = fmaf(w, bf2f(hv[0]), acc0);
      acc1 = fmaf(w, bf2f(hv[1]), acc1);
      acc2 = fmaf(w, bf2f(hv[2]), acc2);
      acc3 = fmaf(w, bf2f(hv[3]), acc3);
    }
    s16x4 pk;
    pk[0] = f2bf(acc0); pk[1] = f2bf(acc1); pk[2] = f2bf(acc2); pk[3] = f2bf(acc3);
    long off = (long)s * DIM + (((g & 8) | ((g & 7) ^ (s & 7))) * 8) + j0;
    *reinterpret_cast<s16x4*>(&P1b[off]) = pk;
  }
}

// zero src-only touched hb rows
static __device__ __forceinline__ void zzero_body(short* __restrict__ hb,
                                                  const int* __restrict__ zl,
                                                  const int* __restrict__ nzp,
                                                  int bid, int nblocks) {
  int nz = nzp[0];
  int l = threadIdx.x & 31;
  s16x4 z = {};
  for (int s = bid * 8 + (threadIdx.x >> 5); s < nz; s += nblocks * 8) {
    *reinterpret_cast<s16x4*>(&hb[(long)zl[s] * DIM + l * 4]) = z;
  }
}

// fused LSTM (2 cols per block, 256 thr): gates, select, hx/cx update, bf16 Wt tiles
static __device__ __forceinline__ void lstm_body(
    int bid, const float* __restrict__ hxc, float* __restrict__ hxn,
    float* __restrict__ cx, const float* __restrict__ Wih,
    const float* __restrict__ Whh, const float* __restrict__ bih,
    const float* __restrict__ bhh, const int* __restrict__ meta,
    short* __restrict__ WtL0, short* __restrict__ WtL1, int t,
    float* wi, float* wh) {
  int tid = threadIdx.x;
  int i = bid >> 6;
  int j2 = bid & 63;
  int jl = tid >> 7;
  int r = tid & 127;
  int j = j2 * 2 + jl;
  float* wiL = wi + jl * 512;
  float* whL = wh + jl * 512;
#pragma unroll
  for (int g4 = 0; g4 < 4; ++g4) {
    wiL[g4 * 128 + r] = Wih[((long)i * 512 + g4 * 128 + j) * DIM + r];
    whL[g4 * 128 + r] = Whh[((long)i * 512 + g4 * 128 + j) * DIM + r];
  }
  __syncthreads();
  const float4* x4 = reinterpret_cast<const float4*>(hxc + ((long)i * DIM + r) * DIM);
  float a0 = 0, a1 = 0, a2 = 0, a3 = 0, b0 = 0, b1 = 0, b2 = 0, b3 = 0;
#pragma unroll 4
  for (int k4 = 0; k4 < 32; ++k4) {
    float4 xv = x4[k4];
    const float* vp = &xv.x;
#pragma unroll
    for (int q = 0; q < 4; ++q) {
      int k = k4 * 4 + q;
      float xs = vp[q];
      a0 = fmaf(xs, wiL[k], a0);       a1 = fmaf(xs, wiL[128 + k], a1);
      a2 = fmaf(xs, wiL[256 + k], a2); a3 = fmaf(xs, wiL[384 + k], a3);
      b0 = fmaf(xs, whL[k], b0);       b1 = fmaf(xs, whL[128 + k], b1);
      b2 = fmaf(xs, whL[256 + k], b2); b3 = fmaf(xs, whL[384 + k], b3);
    }
  }
  int cbi = i * 512 + j;
  float g0i = a0 + bih[cbi] + bhh[cbi];
  float g0f = a1 + bih[cbi + 128] + bhh[cbi + 128];
  float g0g = a2 + bih[cbi + 256] + bhh[cbi + 256];
  float g0o = a3 + bih[cbi + 384] + bhh[cbi + 384];
  float g1i = g0i + b0, g1f = g0f + b1, g1g = g0g + b2, g1o = g0o + b3;
  int idx = i * 16384 + r * 128 + j;
  float c0v = cx[idx];
  float c_zero = sigm(g0i) * tanhf(g0g);
  float h_zero = sigm(g0o) * tanhf(c_zero);
  float c_st = sigm(g1f) * c0v + sigm(g1i) * tanhf(g1g);
  float h_st = sigm(g1o) * tanhf(c_st);
  int first = meta[8 + t];
  int has = meta[t] > 0;
  float hi_v = first ? h_st : h_zero;
  float ci_v = first ? c0v : c_zero;
  float xj = reinterpret_cast<const float*>(x4)[j];
  float hnew = has ? hi_v : xj;
  float cnew = has ? ci_v : c0v;
  hxn[idx] = hnew;
  cx[idx] = cnew;
  short* Wt = i ? WtL1 : WtL0;
  int kb = r >> 6, g = (r >> 3) & 7, jj = r & 7;
  Wt[((kb * DIM + j) * 8 + (g ^ (j & 7))) * 8 + jj] = f2bf(hnew);
}

// ============ kernels ============

// setup0: init state + wemb->bf16 + adaptW->bf16 tiles (merged)
__global__ void k_setup0(const float* __restrict__ gcn, float* __restrict__ hx0,
                         float* __restrict__ cx, int* __restrict__ meta,
                         unsigned* __restrict__ keys, int* __restrict__ hist,
                         int* __restrict__ rowof, unsigned* __restrict__ flagbits,
                         const float* __restrict__ wemb, short* __restrict__ wembb,
                         const float* __restrict__ adW, short* __restrict__ WtAd) {
  int bid = blockIdx.x;
  int tid = threadIdx.x;
  if (bid < B_INITP) {
    int i = bid * 256 + tid;
    if (i < LLAYERS * DIM * DIM) { hx0[i] = gcn[i]; cx[i] = 0.f; }
    if (i < BGRAPH * DIM) keys[i] = 0u;
    if (i < 64) meta[i] = 0;
    if (i < NBINS) { hist[i] = 0; rowof[i] = -1; }
    if (i < (NBINS + 31) / 32) flagbits[i] = 0u;
  } else if (bid < B_INITP + B_PREPW) {
    long i = (long)(bid - B_INITP) * 256 + tid;
    const float4* p = reinterpret_cast<const float4*>(wemb + i * 8);
    float4 v0 = p[0], v1 = p[1];
    s16x8 s;
    s[0] = f2bf(v0.x); s[1] = f2bf(v0.y); s[2] = f2bf(v0.z); s[3] = f2bf(v0.w);
    s[4] = f2bf(v1.x); s[5] = f2bf(v1.y); s[6] = f2bf(v1.z); s[7] = f2bf(v1.w);
    *(s16x8*)&wembb[i * 8] = s;
  } else {
    int idx = (bid - B_INITP - B_PREPW) * 256 + tid;  // < 4096
    int g = idx & 7;
    int c = (idx >> 3) & 127;
    int kb = idx >> 10;
    s16x8 s;
#pragma unroll
    for (int j = 0; j < 8; ++j) s[j] = f2bf(adW[(long)(kb * 64 + g * 8 + j) * DIM + c]);
    *(s16x8*)&WtAd[(((long)kb * DIM + c) * 8 + (g ^ (c & 7))) * 8] = s;
  }
}

// histogram by (t,dst); src flag bits; per-t edge counts
__global__ void k_hist(const int* __restrict__ et, const int* __restrict__ src,
                       const int* __restrict__ dst, int* __restrict__ hist,
                       unsigned* __restrict__ flagbits, int* __restrict__ meta) {
  __shared__ int loc[TSTEPS];
  int tid = threadIdx.x;
  if (tid < TSTEPS) loc[tid] = 0;
  __syncthreads();
  int e = blockIdx.x * blockDim.x + tid;
  if (e < E_EDGES) {
    int t = et[e];
    atomicAdd(&hist[t * N_NODES + dst[e]], 1);
    int fs = t * N_NODES + src[e];
    atomicOr(&flagbits[fs >> 5], 1u << (fs & 31));
    atomicAdd(&loc[t], 1);
  }
  __syncthreads();
  if (tid < TSTEPS && loc[tid]) atomicAdd(&meta[tid], loc[tid]);
}

// fused 2-level exclusive scan: hist values AND nonempty indicator
__global__ void k_scan1b(const int* __restrict__ hist, int* __restrict__ scanv,
                         int* __restrict__ scans, int* __restrict__ bsumA,
                         int* __restrict__ bsumB) {
  __shared__ int shA[256], shB[256];
  int b0 = blockIdx.x * 1024;
  int tid = threadIdx.x;
  int v[4], w[4]; int sA = 0, sB = 0;
#pragma unroll
  for (int q = 0; q < 4; ++q) {
    int i = b0 + tid * 4 + q;
    int c = (i < NBINS) ? hist[i] : 0;
    v[q] = c; w[q] = (c > 0) ? 1 : 0;
    sA += c; sB += w[q];
  }
  shA[tid] = sA; shB[tid] = sB;
  __syncthreads();
  for (int off = 1; off < 256; off <<= 1) {
    int xA = (tid >= off) ? shA[tid - off] : 0;
    int xB = (tid >= off) ? shB[tid - off] : 0;
    __syncthreads();
    shA[tid] += xA; shB[tid] += xB;
    __syncthreads();
  }
  int exA = shA[tid] - sA, exB = shB[tid] - sB;
#pragma unroll
  for (int q = 0; q < 4; ++q) {
    int i = b0 + tid * 4 + q;
    if (i < NBINS) { scanv[i] = exA; scans[i] = exB; }
    exA += v[q]; exB += w[q];
  }
  if (tid == 255) { bsumA[blockIdx.x] = shA[255]; bsumB[blockIdx.x] = shB[255]; }
}

__global__ void k_scan2(int* __restrict__ bsumA, int* __restrict__ bsumB,
                        const int* __restrict__ scans, int* __restrict__ meta) {
  if (blockIdx.x == 0 && threadIdx.x == 0) {
    int sA = 0, sB = 0;
    for (int i = 0; i < NB; ++i) {
      int a = bsumA[i]; bsumA[i] = sA; sA += a;
      int b = bsumB[i]; bsumB[i] = sB; sB += b;
    }
    int f = 0;
    for (int t = 0; t < TSTEPS; ++t) { meta[8 + t] = f; f |= (meta[t] > 0); }
    for (int t = 0; t < TSTEPS; ++t) {
      int lo = scans[t * N_NODES] + bsumB[(t * N_NODES) >> 10];
      int hi = (t == TSTEPS - 1)
                   ? sB
                   : scans[(t + 1) * N_NODES] + bsumB[((t + 1) * N_NODES) >> 10];
      meta[32 + t] = hi - lo;
      meta[48 + t] = lo;
    }
  }
}

// finalize scan; build segments via scan ranks (NO atomics)
__global__ void k_scan3seg(int* __restrict__ scanv, const int* __restrict__ bsumA,
                           const int* __restrict__ scans, const int* __restrict__ bsumB,
                           const int* __restrict__ hist, const int* __restrict__ meta,
                           int* __restrict__ segdst, int* __restrict__ segstart,
                           int* __restrict__ seglen, int* __restrict__ rowof) {
  int i = blockIdx.x * blockDim.x + threadIdx.x;
  if (i >= NBINS) return;
  int vA = scanv[i] + bsumA[i >> 10];
  scanv[i] = vA;
  int c = hist[i];
  if (c > 0) {
    int t = i / N_NODES;
    int tb = t * N_NODES;
    int sidx = scans[i] + bsumB[i >> 10] - meta[48 + t];
    long sb = (long)tb + sidx;
    segdst[sb] = i - tb;
    segstart[sb] = vA;
    seglen[sb] = c;
    rowof[i] = sidx;
  }
}

// setup1: place edges + zlist + table GEMM (merged)
__global__ __launch_bounds__(256) void k_setup1(
    const int* __restrict__ et, const int* __restrict__ src,
    const int* __restrict__ dst, const float* __restrict__ ew,
    int* __restrict__ scanv, const int* __restrict__ rowof,
    int2* __restrict__ sedgeA, int2* __restrict__ sedgeB,
    const unsigned* __restrict__ flagbits, const int* __restrict__ hist,
    int* __restrict__ meta, int* __restrict__ zlist,
    const short* __restrict__ wembb, const short* __restrict__ WtAd,
    const float* __restrict__ adb, short* __restrict__ table16) {
  __shared__ short As[128 * 64];
  __shared__ short Ws[128 * 64];
  __shared__ int zcnt[TSTEPS], zbase[TSTEPS], zcur[TSTEPS];
  int bid = blockIdx.x;
  int tid = threadIdx.x;
  if (bid < B_PLACE) {
    int e = bid * 256 + tid;
    if (e < E_EDGES) {
      int t = et[e];
      int sn = src[e];
      int bin = t * N_NODES + dst[e];
      int pos = atomicAdd(&scanv[bin], 1);
      int wb = __float_as_int(ew[e]);
      sedgeA[pos] = make_int2(sn, wb);
      sedgeB[pos] = make_int2(rowof[t * N_NODES + sn], wb);
    }
  } else if (bid < B_PLACE + B_INITP) {
    if (tid < TSTEPS) { zcnt[tid] = 0; zcur[tid] = 0; }
    __syncthreads();
    int i = (bid - B_PLACE) * 256 + tid;
    int t = -1; bool z = false;
    if (i < NBINS) {
      t = i / N_NODES;
      z = ((flagbits[i >> 5] >> (i & 31)) & 1u) && (hist[i] == 0);
      if (z) atomicAdd(&zcnt[t], 1);
    }
    __syncthreads();
    if (tid < TSTEPS && zcnt[tid]) zbase[tid] = atomicAdd(&meta[40 + tid], zcnt[tid]);
    __syncthreads();
    if (z) {
      int p = atomicAdd(&zcur[t], 1);
      zlist[(long)t * N_NODES + zbase[t] + p] = i - t * N_NODES;
    }
  } else {
    gemm_body<4, 2, false, true, false, false>(wembb, WtAd, adb, table16, nullptr,
                                               NWORDS, nullptr, As, Ws,
                                               bid - B_PLACE - B_INITP);
  }
}

// embed gather: hb[n] = table16[word_ids[n]]
__global__ void k_embed(const short* __restrict__ table16, const int* __restrict__ wid,
                        short* __restrict__ hb) {
  int l = threadIdx.x & 31;
  for (int n = blockIdx.x * 8 + (threadIdx.x >> 5); n < N_NODES; n += gridDim.x * 8) {
    *reinterpret_cast<s16x4*>(&hb[(long)n * DIM + l * 4]) =
        *reinterpret_cast<const s16x4*>(&table16[(long)wid[n] * DIM + l * 4]);
  }
}

// loop launch A: lstm (blocks 0..127) + scat0 (blocks 128..639)
__global__ __launch_bounds__(256) void k_ls(
    const float* __restrict__ hxc, float* __restrict__ hxn, float* __restrict__ cx,
    const float* __restrict__ Wih, const float* __restrict__ Whh,
    const float* __restrict__ bih, const float* __restrict__ bhh,
    const int* __restrict__ meta, short* __restrict__ WtL0, short* __restrict__ WtL1,
    int t, const int* __restrict__ ss, const int* __restrict__ sl,
    const int2* __restrict__ sedgeA, const short* __restrict__ hb,
    short* __restrict__ P1b, const int* __restrict__ nsegp) {
  __shared__ float wi[1024], wh[1024];
  int bid = blockIdx.x;
  if (bid < B_LSTM) {
    lstm_body(bid, hxc, hxn, cx, Wih, Whh, bih, bhh, meta, WtL0, WtL1, t, wi, wh);
  } else {
    segscat_body<false>(ss, sl, sedgeA, hb, P1b, nsegp[0], bid - B_LSTM, B_SCAT);
  }
}

// loop launch B: gemm0 (P2b = relu(P1b @ W0)) + zzero
__global__ __launch_bounds__(256) void k_gz(
    const short* __restrict__ P1b, const short* __restrict__ WtL0,
    short* __restrict__ P2b, const int* __restrict__ nsegp, short* __restrict__ hb,
    const int* __restrict__ zl, const int* __restrict__ nzp) {
  __shared__ short As[128 * 64];
  __shared__ short Ws[128 * 64];
  int bid = blockIdx.x;
  if (bid < GB) {
    gemm_body<2, 0, true, false, true, false>(P1b, WtL0, nullptr, P2b, nullptr, 0,
                                              nsegp, As, Ws, bid);
  } else {
    zzero_body(hb, zl, nzp, bid - GB, B_ZZ);
  }
}

// loop launch C: scat1 (P1b = segscatter(P2b))
__global__ __launch_bounds__(256) void k_s1(
    const int* __restrict__ ss, const int* __restrict__ sl,
    const int2* __restrict__ sedgeB, const short* __restrict__ P2b,
    short* __restrict__ P1b, const int* __restrict__ nsegp) {
  segscat_body<true>(ss, sl, sedgeB, P2b, P1b, nsegp[0], blockIdx.x, B_SCAT);
}

// loop launch D: gemm1 (hb[segdst] = relu(P1b @ W1))
__global__ __launch_bounds__(256) void k_g1(
    const short* __restrict__ P1b, const short* __restrict__ WtL1,
    short* __restrict__ hb, const int* __restrict__ sd, const int* __restrict__ nsegp) {
  __shared__ short As[128 * 64];
  __shared__ short Ws[128 * 64];
  gemm_body<2, 0, true, false, true, true>(P1b, WtL1, nullptr, hb, sd, 0, nsegp,
                                           As, Ws, blockIdx.x);
}

// segment max (graph_id sorted), bf16 input
__global__ void k_segmax(const short* __restrict__ hb, const int* __restrict__ gid,
                         unsigned* __restrict__ keys) {
  int d = threadIdx.x;
  int n0 = blockIdx.x * 64;
  int end = min(n0 + 64, N_NODES);
  if (n0 >= N_NODES) return;
  int curg = gid[n0];
  float m = -INFINITY;
  for (int n = n0; n < end; ++n) {
    int g = gid[n];
    if (g != curg) {
      atomicMax(&keys[(long)curg * DIM + d], fenc(m));
      curg = g;
      m = -INFINITY;
    }
    m = fmaxf(m, bf2f(hb[(long)n * DIM + d]));
  }
  atomicMax(&keys[(long)curg * DIM + d], fenc(m));
}

// final: logits, probs, BCE loss
__global__ void k_final(const unsigned* __restrict__ keys, const float* __restrict__ outW,
                        const float* __restrict__ outB, const float* __restrict__ y,
                        float* __restrict__ out) {
  __shared__ float lt[BGRAPH];
  int tid = threadIdx.x;
  int b = tid >> 2, l4 = tid & 3;
  float s = 0.f;
  for (int d = l4; d < DIM; d += 4) {
    float v = fdec(keys[(long)b * DIM + d]);
    if (!isfinite(v)) v = 0.f;
    s += v * outW[d];
  }
  s += __shfl_down(s, 1);
  s += __shfl_down(s, 2);
  if (l4 == 0) {
    float l = s + outB[0];
    out[1 + b] = 1.f / (1.f + expf(-l));
    lt[b] = fmaxf(l, 0.f) - l * y[b] + log1pf(expf(-fabsf(l)));
  }
  __syncthreads();
  if (tid == 0) {
    float acc = 0.f;
    for (int i = 0; i < BGRAPH; ++i) acc += lt[i];
    out[0] = acc / (float)BGRAPH;
  }
}

extern "C" void kernel_launch(void* const* d_in, const int* in_sizes, int n_in,
                              void* d_out, int out_size, void* d_ws, size_t ws_size,
                              hipStream_t stream) {
  const int* word_ids = (const int*)d_in[0];
  const int* src = (const int*)d_in[1];
  const int* dst = (const int*)d_in[2];
  const int* et = (const int*)d_in[3];
  const float* ew = (const float*)d_in[4];
  const int* gid = (const int*)d_in[5];
  const float* y = (const float*)d_in[6];
  const float* wemb = (const float*)d_in[7];
  const float* adW = (const float*)d_in[8];
  const float* adb = (const float*)d_in[9];
  const float* gcn = (const float*)d_in[10];
  const float* Wih = (const float*)d_in[11];
  const float* Whh = (const float*)d_in[12];
  const float* bih = (const float*)d_in[13];
  const float* bhh = (const float*)d_in[14];
  const float* outW = (const float*)d_in[15];
  const float* outB = (const float*)d_in[16];
  float* out = (float*)d_out;

  char* ws = (char*)d_ws;
  const long ND = (long)N_NODES * DIM;
  short* hb = (short*)ws;       ws += ND * 2;
  short* P1b = (short*)ws;      ws += ND * 2;
  short* P2b = (short*)ws;      ws += ND * 2;
  float* hxA = (float*)ws;      ws += LLAYERS * DIM * DIM * 4;
  float* hxB = (float*)ws;      ws += LLAYERS * DIM * DIM * 4;
  float* cx = (float*)ws;       ws += LLAYERS * DIM * DIM * 4;
  int* meta = (int*)ws;         ws += 64 * 4;
  unsigned* keys = (unsigned*)ws; ws += BGRAPH * DIM * 4;
  int* hist = (int*)ws;         ws += (long)NBINS * 4;
  int* scanv = (int*)ws;        ws += (long)NBINS * 4;
  int* scans = (int*)ws;        ws += (long)NBINS * 4;
  int* bsumA = (int*)ws;        ws += ((NB + 63) & ~63) * 4;
  int* bsumB = (int*)ws;        ws += ((NB + 63) & ~63) * 4;
  int* rowof = (int*)ws;        ws += (long)NBINS * 4;
  int* segdst = (int*)ws;       ws += (long)NBINS * 4;
  int* segstart = (int*)ws;     ws += (long)NBINS * 4;
  int* seglen = (int*)ws;       ws += (long)NBINS * 4;
  int* zlist = (int*)ws;        ws += (long)NBINS * 4;
  int2* sedgeA = (int2*)ws;     ws += (long)E_EDGES * 8;
  int2* sedgeB = (int2*)ws;     ws += (long)E_EDGES * 8;
  unsigned* flagbits = (unsigned*)ws; ws += ((NBINS + 31) / 32 + 64) * 4;
  short* wembb = (short*)ws;    ws += (long)NWORDS * NINPK * 2;
  short* table16 = (short*)ws;  ws += (long)NWORDS * DIM * 2;
  short* WtAd = (short*)ws;     ws += 4L * DIM * 64 * 2;
  short* WtL0 = (short*)ws;     ws += 2L * DIM * 64 * 2;
  short* WtL1 = (short*)ws;     ws += 2L * DIM * 64 * 2;

  // ---- setup (7 launches) ----
  k_setup0<<<B_INITP + B_PREPW + B_PREP, 256, 0, stream>>>(
      gcn, hxA, cx, meta, keys, hist, rowof, flagbits, wemb, wembb, adW, WtAd);
  k_hist<<<(E_EDGES + 255) / 256, 256, 0, stream>>>(et, src, dst, hist, flagbits, meta);
  k_scan1b<<<NB, 256, 0, stream>>>(hist, scanv, scans, bsumA, bsumB);
  k_scan2<<<1, 64, 0, stream>>>(bsumA, bsumB, scans, meta);
  k_scan3seg<<<B_INITP, 256, 0, stream>>>(scanv, bsumA, scans, bsumB, hist, meta,
                                          segdst, segstart, seglen, rowof);
  k_setup1<<<B_PLACE + B_INITP + B_TGEMM, 256, 0, stream>>>(
      et, src, dst, ew, scanv, rowof, sedgeA, sedgeB, flagbits, hist, meta, zlist,
      wembb, WtAd, adb, table16);
  k_embed<<<1024, 256, 0, stream>>>(table16, word_ids, hb);

  // ---- t-loop (4 launches per step) ----
  for (int t = 0; t < TSTEPS; ++t) {
    const int* nsegp = &meta[32 + t];
    const int* nzp = &meta[40 + t];
    const int* ss = segstart + (long)t * N_NODES;
    const int* sl = seglen + (long)t * N_NODES;
    const int* sd = segdst + (long)t * N_NODES;
    const int* zl = zlist + (long)t * N_NODES;
    const float* hxc = (t & 1) ? hxB : hxA;
    float* hxn = (t & 1) ? hxA : hxB;
    k_ls<<<B_LSTM + B_SCAT, 256, 0, stream>>>(hxc, hxn, cx, Wih, Whh, bih, bhh,
                                              meta, WtL0, WtL1, t, ss, sl, sedgeA,
                                              hb, P1b, nsegp);
    k_gz<<<GB + B_ZZ, 256, 0, stream>>>(P1b, WtL0, P2b, nsegp, hb, zl, nzp);
    k_s1<<<B_SCAT, 256, 0, stream>>>(ss, sl, sedgeB, P2b, P1b, nsegp);
    k_g1<<<GB, 256, 0, stream>>>(P1b, WtL1, hb, sd, nsegp);
  }

  k_segmax<<<(N_NODES + 63) / 64, 128, 0, stream>>>(hb, gid, keys);
  k_final<<<1, 64, 0, stream>>>(keys, outW, outB, y, out);
}

// Round 8
// 395.893 us; speedup vs baseline: 8.3082x; 1.0347x over previous
//
#include <hip/hip_runtime.h>
#include <hip/hip_bf16.h>
#include <math.h>

#define N_NODES 60000
#define E_EDGES 200000
#define DIM     128
#define NINPK   256
#define TSTEPS  6
#define LLAYERS 2
#define BGRAPH  16
#define NBINS   (TSTEPS * N_NODES)          // 360000
#define NB      ((NBINS + 1023) / 1024)     // 352 scan blocks
#define NWORDS  15000

#define B_INITP  ((NBINS + 255) / 256)          // 1407
#define B_PREPW  (NWORDS * NINPK / 8 / 256)     // 1875
#define B_PREP   16
#define B_HIST   ((E_EDGES + 255) / 256)        // 782
#define B_TGEMM  ((NWORDS + 127) / 128)         // 118
#define B_PLACE  ((E_EDGES + 255) / 256)        // 782
#define B_EMBED  512
#define GB       ((N_NODES + 127) / 128)        // 469 gemm blocks (dyn early-exit)
#define B_SCAT   512
#define B_LSTM   128
#define B_ZZ     64

typedef float f32x4 __attribute__((ext_vector_type(4)));
typedef short s16x8 __attribute__((ext_vector_type(8)));
typedef short s16x4 __attribute__((ext_vector_type(4)));

static __device__ __forceinline__ float sigm(float x) { return 1.f / (1.f + expf(-x)); }

static __device__ __forceinline__ short f2bf(float f) {
  unsigned u = __float_as_uint(f);
  u += 0x7FFFu + ((u >> 16) & 1u);
  return (short)(u >> 16);
}
static __device__ __forceinline__ float bf2f(short s) {
  return __uint_as_float(((unsigned)(unsigned short)s) << 16);
}
static __device__ __forceinline__ unsigned fenc(float f) {
  unsigned u = __float_as_uint(f);
  return (u & 0x80000000u) ? ~u : (u | 0x80000000u);
}
static __device__ __forceinline__ float fdec(unsigned u) {
  u = (u & 0x80000000u) ? (u & 0x7fffffffu) : ~u;
  return __uint_as_float(u);
}

// ============ device bodies ============

// GEMM: C16[row] = act(A16 @ Wt (+bias)). MODE 0: A pre-swizzled; MODE 2: linear rows.
template <int KTILES, int MODE, bool RELU, bool BIAS, bool DYN, bool GOUT>
static __device__ __forceinline__ void gemm_body(
    const short* __restrict__ A16, const short* __restrict__ Wt,
    const float* __restrict__ bias, short* __restrict__ C16,
    const int* __restrict__ dstmap, int Nc, const int* __restrict__ nptr,
    short* As, short* Ws, int bid) {
  const int N = DYN ? nptr[0] : Nc;
  const int n0 = bid * 128;
  if (n0 >= N) return;
  const int tid = threadIdx.x;
  const int lane = tid & 63;
  const int w = tid >> 6;
  f32x4 acc[2][8] = {};
  for (int kt = 0; kt < KTILES; ++kt) {
    __syncthreads();
#pragma unroll
    for (int p = 0; p < 4; ++p) {
      int gi = p * 256 + tid;
      int row = gi >> 3, s = gi & 7;
      int n = n0 + row;
      s16x8 v = {};
      if (n < N) {
        if (MODE == 0) {
          v = *(const s16x8*)&A16[(long)n * (KTILES * 64) + kt * 64 + s * 8];
        } else {
          v = *(const s16x8*)&A16[(long)n * (KTILES * 64) + kt * 64 + (s ^ (row & 7)) * 8];
        }
      }
      *(s16x8*)&As[(row * 8 + s) * 8] = v;
    }
    const int4* wg = reinterpret_cast<const int4*>(Wt + kt * 128 * 64);
    int4* wl = reinterpret_cast<int4*>(Ws);
#pragma unroll
    for (int p = 0; p < 4; ++p) wl[p * 256 + tid] = wg[p * 256 + tid];
    __syncthreads();
#pragma unroll
    for (int kk = 0; kk < 2; ++kk) {
      int gb = kk * 4 + (lane >> 4);
      s16x8 a[2];
#pragma unroll
      for (int fr = 0; fr < 2; ++fr) {
        int row = w * 32 + fr * 16 + (lane & 15);
        a[fr] = *(const s16x8*)&As[(row * 8 + (gb ^ (row & 7))) * 8];
      }
#pragma unroll
      for (int fc = 0; fc < 8; ++fc) {
        int col = fc * 16 + (lane & 15);
        s16x8 b = *(const s16x8*)&Ws[(col * 8 + (gb ^ (col & 7))) * 8];
        acc[0][fc] = __builtin_amdgcn_mfma_f32_16x16x32_bf16(a[0], b, acc[0][fc], 0, 0, 0);
        acc[1][fc] = __builtin_amdgcn_mfma_f32_16x16x32_bf16(a[1], b, acc[1][fc], 0, 0, 0);
      }
    }
  }
  // epilogue: C/D layout col=lane&15, row=(lane>>4)*4+reg  [m89-verified]
  const int cb = lane & 15;
  const int rb = w * 32 + (lane >> 4) * 4;
#pragma unroll
  for (int fr = 0; fr < 2; ++fr) {
#pragma unroll
    for (int reg = 0; reg < 4; ++reg) {
      int n = n0 + rb + fr * 16 + reg;
      if (n >= N) continue;
      long drow = GOUT ? (long)dstmap[n] : (long)n;
      short* cp = C16 + drow * DIM;
#pragma unroll
      for (int fc = 0; fc < 8; ++fc) {
        float x = acc[fr][fc][reg];
        if (BIAS) x += bias[fc * 16 + cb];
        if (RELU) x = fmaxf(x, 0.f);
        cp[fc * 16 + cb] = f2bf(x);
      }
    }
  }
}

// segmented scatter: P1b[s] (pre-swizzled) = bf16(sum_e w_e * IN16[row_e])
// sedge: {src_node, w_bits}. PACKEDIN: row = ro[src] (may be -1: skip).
template <bool PACKEDIN>
static __device__ __forceinline__ void segscat_body(
    const int* __restrict__ segstart, const int* __restrict__ seglen,
    const int2* __restrict__ sedge, const short* __restrict__ IN16,
    const int* __restrict__ ro, short* __restrict__ P1b, int nseg, int bid,
    int nblocks) {
  int gsz = nblocks * 8;
  int l = threadIdx.x & 31;
  int d4 = l << 2;
  int g = l >> 1, j0 = (l & 1) * 4;
  for (int s = bid * 8 + (threadIdx.x >> 5); s < nseg; s += gsz) {
    int st = segstart[s], len = seglen[s];
    float acc0 = 0.f, acc1 = 0.f, acc2 = 0.f, acc3 = 0.f;
    for (int e = st; e < st + len; ++e) {
      int2 v = sedge[e];
      int row = PACKEDIN ? ro[v.x] : v.x;
      if (PACKEDIN && row < 0) continue;
      float w = __int_as_float(v.y);
      s16x4 hv = *reinterpret_cast<const s16x4*>(&IN16[(long)row * DIM + d4]);
      acc0 = fmaf(w, bf2f(hv[0]), acc0);
      acc1 = fmaf(w, bf2f(hv[1]), acc1);
      acc2 = fmaf(w, bf2f(hv[2]), acc2);
      acc3 = fmaf(w, bf2f(hv[3]), acc3);
    }
    s16x4 pk;
    pk[0] = f2bf(acc0); pk[1] = f2bf(acc1); pk[2] = f2bf(acc2); pk[3] = f2bf(acc3);
    long off = (long)s * DIM + (((g & 8) | ((g & 7) ^ (s & 7))) * 8) + j0;
    *reinterpret_cast<s16x4*>(&P1b[off]) = pk;
  }
}

// zero src-only touched hb rows
static __device__ __forceinline__ void zzero_body(short* __restrict__ hb,
                                                  const int* __restrict__ zl,
                                                  const int* __restrict__ nzp,
                                                  int bid, int nblocks) {
  int nz = nzp[0];
  int l = threadIdx.x & 31;
  s16x4 z = {};
  for (int s = bid * 8 + (threadIdx.x >> 5); s < nz; s += nblocks * 8) {
    *reinterpret_cast<s16x4*>(&hb[(long)zl[s] * DIM + l * 4]) = z;
  }
}

// fused LSTM (2 cols per block, 256 thr): gates, select, hx/cx update, bf16 Wt tiles
static __device__ __forceinline__ void lstm_body(
    int bid, const float* __restrict__ hxc, float* __restrict__ hxn,
    float* __restrict__ cx, const float* __restrict__ Wih,
    const float* __restrict__ Whh, const float* __restrict__ bih,
    const float* __restrict__ bhh, const int* __restrict__ meta,
    short* __restrict__ WtL0, short* __restrict__ WtL1, int t,
    float* wi, float* wh) {
  int tid = threadIdx.x;
  int i = bid >> 6;
  int j2 = bid & 63;
  int jl = tid >> 7;
  int r = tid & 127;
  int j = j2 * 2 + jl;
  float* wiL = wi + jl * 512;
  float* whL = wh + jl * 512;
#pragma unroll
  for (int g4 = 0; g4 < 4; ++g4) {
    wiL[g4 * 128 + r] = Wih[((long)i * 512 + g4 * 128 + j) * DIM + r];
    whL[g4 * 128 + r] = Whh[((long)i * 512 + g4 * 128 + j) * DIM + r];
  }
  __syncthreads();
  const float4* x4 = reinterpret_cast<const float4*>(hxc + ((long)i * DIM + r) * DIM);
  float a0 = 0, a1 = 0, a2 = 0, a3 = 0, b0 = 0, b1 = 0, b2 = 0, b3 = 0;
#pragma unroll 4
  for (int k4 = 0; k4 < 32; ++k4) {
    float4 xv = x4[k4];
    const float* vp = &xv.x;
#pragma unroll
    for (int q = 0; q < 4; ++q) {
      int k = k4 * 4 + q;
      float xs = vp[q];
      a0 = fmaf(xs, wiL[k], a0);       a1 = fmaf(xs, wiL[128 + k], a1);
      a2 = fmaf(xs, wiL[256 + k], a2); a3 = fmaf(xs, wiL[384 + k], a3);
      b0 = fmaf(xs, whL[k], b0);       b1 = fmaf(xs, whL[128 + k], b1);
      b2 = fmaf(xs, whL[256 + k], b2); b3 = fmaf(xs, whL[384 + k], b3);
    }
  }
  int cbi = i * 512 + j;
  float g0i = a0 + bih[cbi] + bhh[cbi];
  float g0f = a1 + bih[cbi + 128] + bhh[cbi + 128];
  float g0g = a2 + bih[cbi + 256] + bhh[cbi + 256];
  float g0o = a3 + bih[cbi + 384] + bhh[cbi + 384];
  float g1i = g0i + b0, g1f = g0f + b1, g1g = g0g + b2, g1o = g0o + b3;
  int idx = i * 16384 + r * 128 + j;
  float c0v = cx[idx];
  float c_zero = sigm(g0i) * tanhf(g0g);
  float h_zero = sigm(g0o) * tanhf(c_zero);
  float c_st = sigm(g1f) * c0v + sigm(g1i) * tanhf(g1g);
  float h_st = sigm(g1o) * tanhf(c_st);
  int first = meta[8 + t];
  int has = meta[t] > 0;
  float hi_v = first ? h_st : h_zero;
  float ci_v = first ? c0v : c_zero;
  float xj = reinterpret_cast<const float*>(x4)[j];
  float hnew = has ? hi_v : xj;
  float cnew = has ? ci_v : c0v;
  hxn[idx] = hnew;
  cx[idx] = cnew;
  short* Wt = i ? WtL1 : WtL0;
  int kb = r >> 6, g = (r >> 3) & 7, jj = r & 7;
  Wt[((kb * DIM + j) * 8 + (g ^ (j & 7))) * 8 + jj] = f2bf(hnew);
}

// ============ kernels ============

// setup0: init state + wemb->bf16 + adaptW->bf16 tiles (merged)
__global__ void k_setup0(const float* __restrict__ gcn, float* __restrict__ hx0,
                         float* __restrict__ cx, int* __restrict__ meta,
                         unsigned* __restrict__ keys, int* __restrict__ hist,
                         int* __restrict__ rowof, unsigned* __restrict__ flagbits,
                         const float* __restrict__ wemb, short* __restrict__ wembb,
                         const float* __restrict__ adW, short* __restrict__ WtAd) {
  int bid = blockIdx.x;
  int tid = threadIdx.x;
  if (bid < B_INITP) {
    int i = bid * 256 + tid;
    if (i < LLAYERS * DIM * DIM) { hx0[i] = gcn[i]; cx[i] = 0.f; }
    if (i < BGRAPH * DIM) keys[i] = 0u;
    if (i < 64) meta[i] = 0;
    if (i < NBINS) { hist[i] = 0; rowof[i] = -1; }
    if (i < (NBINS + 31) / 32) flagbits[i] = 0u;
  } else if (bid < B_INITP + B_PREPW) {
    long i = (long)(bid - B_INITP) * 256 + tid;
    const float4* p = reinterpret_cast<const float4*>(wemb + i * 8);
    float4 v0 = p[0], v1 = p[1];
    s16x8 s;
    s[0] = f2bf(v0.x); s[1] = f2bf(v0.y); s[2] = f2bf(v0.z); s[3] = f2bf(v0.w);
    s[4] = f2bf(v1.x); s[5] = f2bf(v1.y); s[6] = f2bf(v1.z); s[7] = f2bf(v1.w);
    *(s16x8*)&wembb[i * 8] = s;
  } else {
    int idx = (bid - B_INITP - B_PREPW) * 256 + tid;  // < 4096
    int g = idx & 7;
    int c = (idx >> 3) & 127;
    int kb = idx >> 10;
    s16x8 s;
#pragma unroll
    for (int j = 0; j < 8; ++j) s[j] = f2bf(adW[(long)(kb * 64 + g * 8 + j) * DIM + c]);
    *(s16x8*)&WtAd[(((long)kb * DIM + c) * 8 + (g ^ (c & 7))) * 8] = s;
  }
}

// hist atomics (no LDS counters) + table GEMM (merged)
__global__ __launch_bounds__(256) void k_histg(
    const int* __restrict__ et, const int* __restrict__ src,
    const int* __restrict__ dst, int* __restrict__ hist,
    unsigned* __restrict__ flagbits, const short* __restrict__ wembb,
    const short* __restrict__ WtAd, const float* __restrict__ adb,
    short* __restrict__ table16) {
  __shared__ short As[128 * 64];
  __shared__ short Ws[128 * 64];
  int bid = blockIdx.x;
  if (bid < B_HIST) {
    int e = bid * 256 + threadIdx.x;
    if (e < E_EDGES) {
      int t = et[e];
      atomicAdd(&hist[t * N_NODES + dst[e]], 1);
      int fs = t * N_NODES + src[e];
      atomicOr(&flagbits[fs >> 5], 1u << (fs & 31));
    }
  } else {
    gemm_body<4, 2, false, true, false, false>(wembb, WtAd, adb, table16, nullptr,
                                               NWORDS, nullptr, As, Ws, bid - B_HIST);
  }
}

// fused 2-level exclusive scan: hist values, nonempty indicator, z indicator
__global__ void k_scan1b(const int* __restrict__ hist,
                         const unsigned* __restrict__ flagbits,
                         int* __restrict__ scanA, int* __restrict__ scanB,
                         int* __restrict__ scanC, int* __restrict__ bsumA,
                         int* __restrict__ bsumB, int* __restrict__ bsumC) {
  __shared__ int shA[256], shB[256], shC[256];
  int b0 = blockIdx.x * 1024;
  int tid = threadIdx.x;
  int v[4], w[4], z[4];
  int sA = 0, sB = 0, sC = 0;
#pragma unroll
  for (int q = 0; q < 4; ++q) {
    int i = b0 + tid * 4 + q;
    int c = (i < NBINS) ? hist[i] : 0;
    int fl = (i < NBINS) ? (int)((flagbits[i >> 5] >> (i & 31)) & 1u) : 0;
    v[q] = c; w[q] = (c > 0) ? 1 : 0; z[q] = (fl && c == 0) ? 1 : 0;
    sA += c; sB += w[q]; sC += z[q];
  }
  shA[tid] = sA; shB[tid] = sB; shC[tid] = sC;
  __syncthreads();
  for (int off = 1; off < 256; off <<= 1) {
    int xA = (tid >= off) ? shA[tid - off] : 0;
    int xB = (tid >= off) ? shB[tid - off] : 0;
    int xC = (tid >= off) ? shC[tid - off] : 0;
    __syncthreads();
    shA[tid] += xA; shB[tid] += xB; shC[tid] += xC;
    __syncthreads();
  }
  int exA = shA[tid] - sA, exB = shB[tid] - sB, exC = shC[tid] - sC;
#pragma unroll
  for (int q = 0; q < 4; ++q) {
    int i = b0 + tid * 4 + q;
    if (i < NBINS) { scanA[i] = exA; scanB[i] = exB; scanC[i] = exC; }
    exA += v[q]; exB += w[q]; exC += z[q];
  }
  if (tid == 255) {
    bsumA[blockIdx.x] = shA[255];
    bsumB[blockIdx.x] = shB[255];
    bsumC[blockIdx.x] = shC[255];
  }
}

// parallel block-sum scan (3 channels) + all meta fields
__global__ __launch_bounds__(256) void k_scan2p(
    int* __restrict__ bsumA, int* __restrict__ bsumB, int* __restrict__ bsumC,
    const int* __restrict__ scanA, const int* __restrict__ scanB,
    const int* __restrict__ scanC, int* __restrict__ meta) {
  __shared__ int pA[256], pB[256], pC[256];
  __shared__ int eA[512], eB[512], eC[512];
  int tid = threadIdx.x;
  int i0 = tid * 2, i1 = tid * 2 + 1;
  int a0 = (i0 < NB) ? bsumA[i0] : 0, a1 = (i1 < NB) ? bsumA[i1] : 0;
  int b0 = (i0 < NB) ? bsumB[i0] : 0, b1 = (i1 < NB) ? bsumB[i1] : 0;
  int c0 = (i0 < NB) ? bsumC[i0] : 0, c1 = (i1 < NB) ? bsumC[i1] : 0;
  int tA = a0 + a1, tB = b0 + b1, tC = c0 + c1;
  pA[tid] = tA; pB[tid] = tB; pC[tid] = tC;
  __syncthreads();
  for (int off = 1; off < 256; off <<= 1) {
    int xA = (tid >= off) ? pA[tid - off] : 0;
    int xB = (tid >= off) ? pB[tid - off] : 0;
    int xC = (tid >= off) ? pC[tid - off] : 0;
    __syncthreads();
    pA[tid] += xA; pB[tid] += xB; pC[tid] += xC;
    __syncthreads();
  }
  int baseA = pA[tid] - tA, baseB = pB[tid] - tB, baseC = pC[tid] - tC;
  eA[i0] = baseA; eA[i1] = baseA + a0;
  eB[i0] = baseB; eB[i1] = baseB + b0;
  eC[i0] = baseC; eC[i1] = baseC + c0;
  if (i0 < NB) { bsumA[i0] = baseA; bsumB[i0] = baseB; bsumC[i0] = baseC; }
  if (i1 < NB) { bsumA[i1] = baseA + a0; bsumB[i1] = baseB + b0; bsumC[i1] = baseC + c0; }
  __syncthreads();
  if (tid == 0) {
    int loA[TSTEPS + 1], loB[TSTEPS + 1], loC[TSTEPS + 1];
    for (int t = 0; t < TSTEPS; ++t) {
      int ib = t * N_NODES, blk = ib >> 10;
      loA[t] = scanA[ib] + eA[blk];
      loB[t] = scanB[ib] + eB[blk];
      loC[t] = scanC[ib] + eC[blk];
    }
    loA[TSTEPS] = pA[255]; loB[TSTEPS] = pB[255]; loC[TSTEPS] = pC[255];
    int f = 0;
    for (int t = 0; t < TSTEPS; ++t) {
      int cnt = loA[t + 1] - loA[t];
      meta[t] = cnt;
      meta[8 + t] = f; f |= (cnt > 0);
      meta[32 + t] = loB[t + 1] - loB[t];   // segcnt
      meta[48 + t] = loB[t];                // seg rank base
      meta[40 + t] = loC[t + 1] - loC[t];   // zcnt
      meta[56 + t] = loC[t];                // z rank base
    }
  }
}

// finalize scan; build segments + rowof + zlist via scan ranks (NO atomics)
__global__ void k_scan3seg(int* __restrict__ scanA, const int* __restrict__ bsumA,
                           const int* __restrict__ scanB, const int* __restrict__ bsumB,
                           const int* __restrict__ scanC, const int* __restrict__ bsumC,
                           const int* __restrict__ hist,
                           const unsigned* __restrict__ flagbits,
                           const int* __restrict__ meta, int* __restrict__ segdst,
                           int* __restrict__ segstart, int* __restrict__ seglen,
                           int* __restrict__ rowof, int* __restrict__ zlist) {
  int i = blockIdx.x * blockDim.x + threadIdx.x;
  if (i >= NBINS) return;
  int vA = scanA[i] + bsumA[i >> 10];
  scanA[i] = vA;
  int c = hist[i];
  int t = i / N_NODES;
  int tb = t * N_NODES;
  if (c > 0) {
    int sidx = scanB[i] + bsumB[i >> 10] - meta[48 + t];
    long sb = (long)tb + sidx;
    segdst[sb] = i - tb;
    segstart[sb] = vA;
    seglen[sb] = c;
    rowof[i] = sidx;
  } else if ((flagbits[i >> 5] >> (i & 31)) & 1u) {
    int zr = scanC[i] + bsumC[i >> 10] - meta[56 + t];
    zlist[(long)tb + zr] = i - tb;
  }
}

// setup1: place edges (single sedge array) + embed gather (merged)
__global__ __launch_bounds__(256) void k_setup1(
    const int* __restrict__ et, const int* __restrict__ src,
    const int* __restrict__ dst, const float* __restrict__ ew,
    int* __restrict__ scanA, int2* __restrict__ sedge,
    const short* __restrict__ table16, const int* __restrict__ wid,
    short* __restrict__ hb) {
  int bid = blockIdx.x;
  int tid = threadIdx.x;
  if (bid < B_PLACE) {
    int e = bid * 256 + tid;
    if (e < E_EDGES) {
      int t = et[e];
      int bin = t * N_NODES + dst[e];
      int pos = atomicAdd(&scanA[bin], 1);
      sedge[pos] = make_int2(src[e], __float_as_int(ew[e]));
    }
  } else {
    int l = tid & 31;
    for (int n = (bid - B_PLACE) * 8 + (tid >> 5); n < N_NODES; n += B_EMBED * 8) {
      *reinterpret_cast<s16x4*>(&hb[(long)n * DIM + l * 4]) =
          *reinterpret_cast<const s16x4*>(&table16[(long)wid[n] * DIM + l * 4]);
    }
  }
}

// loop launch A: lstm (blocks 0..127) + scat0
__global__ __launch_bounds__(256) void k_ls(
    const float* __restrict__ hxc, float* __restrict__ hxn, float* __restrict__ cx,
    const float* __restrict__ Wih, const float* __restrict__ Whh,
    const float* __restrict__ bih, const float* __restrict__ bhh,
    const int* __restrict__ meta, short* __restrict__ WtL0, short* __restrict__ WtL1,
    int t, const int* __restrict__ ss, const int* __restrict__ sl,
    const int2* __restrict__ sedge, const short* __restrict__ hb,
    short* __restrict__ P1b, const int* __restrict__ nsegp) {
  __shared__ float wi[1024], wh[1024];
  int bid = blockIdx.x;
  if (bid < B_LSTM) {
    lstm_body(bid, hxc, hxn, cx, Wih, Whh, bih, bhh, meta, WtL0, WtL1, t, wi, wh);
  } else {
    segscat_body<false>(ss, sl, sedge, hb, nullptr, P1b, nsegp[0], bid - B_LSTM,
                        B_SCAT);
  }
}

// loop launch B: gemm0 (P2b = relu(P1b @ W0)) + zzero
__global__ __launch_bounds__(256) void k_gz(
    const short* __restrict__ P1b, const short* __restrict__ WtL0,
    short* __restrict__ P2b, const int* __restrict__ nsegp, short* __restrict__ hb,
    const int* __restrict__ zl, const int* __restrict__ nzp) {
  __shared__ short As[128 * 64];
  __shared__ short Ws[128 * 64];
  int bid = blockIdx.x;
  if (bid < GB) {
    gemm_body<2, 0, true, false, true, false>(P1b, WtL0, nullptr, P2b, nullptr, 0,
                                              nsegp, As, Ws, bid);
  } else {
    zzero_body(hb, zl, nzp, bid - GB, B_ZZ);
  }
}

// loop launch C: scat1 (P1b = segscatter(P2b via rowof))
__global__ __launch_bounds__(256) void k_s1(
    const int* __restrict__ ss, const int* __restrict__ sl,
    const int2* __restrict__ sedge, const short* __restrict__ P2b,
    const int* __restrict__ ro, short* __restrict__ P1b,
    const int* __restrict__ nsegp) {
  segscat_body<true>(ss, sl, sedge, P2b, ro, P1b, nsegp[0], blockIdx.x, B_SCAT);
}

// loop launch D: gemm1 (hb[segdst] = relu(P1b @ W1))
__global__ __launch_bounds__(256) void k_g1(
    const short* __restrict__ P1b, const short* __restrict__ WtL1,
    short* __restrict__ hb, const int* __restrict__ sd,
    const int* __restrict__ nsegp) {
  __shared__ short As[128 * 64];
  __shared__ short Ws[128 * 64];
  gemm_body<2, 0, true, false, true, true>(P1b, WtL1, nullptr, hb, sd, 0, nsegp,
                                           As, Ws, blockIdx.x);
}

// segment max (graph_id sorted), bf16 input
__global__ void k_segmax(const short* __restrict__ hb, const int* __restrict__ gid,
                         unsigned* __restrict__ keys) {
  int d = threadIdx.x;
  int n0 = blockIdx.x * 64;
  int end = min(n0 + 64, N_NODES);
  if (n0 >= N_NODES) return;
  int curg = gid[n0];
  float m = -INFINITY;
  for (int n = n0; n < end; ++n) {
    int g = gid[n];
    if (g != curg) {
      atomicMax(&keys[(long)curg * DIM + d], fenc(m));
      curg = g;
      m = -INFINITY;
    }
    m = fmaxf(m, bf2f(hb[(long)n * DIM + d]));
  }
  atomicMax(&keys[(long)curg * DIM + d], fenc(m));
}

// final: logits, probs, BCE loss
__global__ void k_final(const unsigned* __restrict__ keys, const float* __restrict__ outW,
                        const float* __restrict__ outB, const float* __restrict__ y,
                        float* __restrict__ out) {
  __shared__ float lt[BGRAPH];
  int tid = threadIdx.x;
  int b = tid >> 2, l4 = tid & 3;
  float s = 0.f;
  for (int d = l4; d < DIM; d += 4) {
    float v = fdec(keys[(long)b * DIM + d]);
    if (!isfinite(v)) v = 0.f;
    s += v * outW[d];
  }
  s += __shfl_down(s, 1);
  s += __shfl_down(s, 2);
  if (l4 == 0) {
    float l = s + outB[0];
    out[1 + b] = 1.f / (1.f + expf(-l));
    lt[b] = fmaxf(l, 0.f) - l * y[b] + log1pf(expf(-fabsf(l)));
  }
  __syncthreads();
  if (tid == 0) {
    float acc = 0.f;
    for (int i = 0; i < BGRAPH; ++i) acc += lt[i];
    out[0] = acc / (float)BGRAPH;
  }
}

extern "C" void kernel_launch(void* const* d_in, const int* in_sizes, int n_in,
                              void* d_out, int out_size, void* d_ws, size_t ws_size,
                              hipStream_t stream) {
  const int* word_ids = (const int*)d_in[0];
  const int* src = (const int*)d_in[1];
  const int* dst = (const int*)d_in[2];
  const int* et = (const int*)d_in[3];
  const float* ew = (const float*)d_in[4];
  const int* gid = (const int*)d_in[5];
  const float* y = (const float*)d_in[6];
  const float* wemb = (const float*)d_in[7];
  const float* adW = (const float*)d_in[8];
  const float* adb = (const float*)d_in[9];
  const float* gcn = (const float*)d_in[10];
  const float* Wih = (const float*)d_in[11];
  const float* Whh = (const float*)d_in[12];
  const float* bih = (const float*)d_in[13];
  const float* bhh = (const float*)d_in[14];
  const float* outW = (const float*)d_in[15];
  const float* outB = (const float*)d_in[16];
  float* out = (float*)d_out;

  char* ws = (char*)d_ws;
  const long ND = (long)N_NODES * DIM;
  short* hb = (short*)ws;       ws += ND * 2;
  short* P1b = (short*)ws;      ws += ND * 2;
  short* P2b = (short*)ws;      ws += ND * 2;
  float* hxA = (float*)ws;      ws += LLAYERS * DIM * DIM * 4;
  float* hxB = (float*)ws;      ws += LLAYERS * DIM * DIM * 4;
  float* cx = (float*)ws;       ws += LLAYERS * DIM * DIM * 4;
  int* meta = (int*)ws;         ws += 64 * 4;
  unsigned* keys = (unsigned*)ws; ws += BGRAPH * DIM * 4;
  int* hist = (int*)ws;         ws += (long)NBINS * 4;
  int* scanA = (int*)ws;        ws += (long)NBINS * 4;
  int* scanB = (int*)ws;        ws += (long)NBINS * 4;
  int* scanC = (int*)ws;        ws += (long)NBINS * 4;
  int* bsumA = (int*)ws;        ws += ((NB + 63) & ~63) * 4;
  int* bsumB = (int*)ws;        ws += ((NB + 63) & ~63) * 4;
  int* bsumC = (int*)ws;        ws += ((NB + 63) & ~63) * 4;
  int* rowof = (int*)ws;        ws += (long)NBINS * 4;
  int* segdst = (int*)ws;       ws += (long)NBINS * 4;
  int* segstart = (int*)ws;     ws += (long)NBINS * 4;
  int* seglen = (int*)ws;       ws += (long)NBINS * 4;
  int* zlist = (int*)ws;        ws += (long)NBINS * 4;
  int2* sedge = (int2*)ws;      ws += (long)E_EDGES * 8;
  unsigned* flagbits = (unsigned*)ws; ws += ((NBINS + 31) / 32 + 64) * 4;
  short* wembb = (short*)ws;    ws += (long)NWORDS * NINPK * 2;
  short* table16 = (short*)ws;  ws += (long)NWORDS * DIM * 2;
  short* WtAd = (short*)ws;     ws += 4L * DIM * 64 * 2;
  short* WtL0 = (short*)ws;     ws += 2L * DIM * 64 * 2;
  short* WtL1 = (short*)ws;     ws += 2L * DIM * 64 * 2;

  // ---- setup (6 launches) ----
  k_setup0<<<B_INITP + B_PREPW + B_PREP, 256, 0, stream>>>(
      gcn, hxA, cx, meta, keys, hist, rowof, flagbits, wemb, wembb, adW, WtAd);
  k_histg<<<B_HIST + B_TGEMM, 256, 0, stream>>>(et, src, dst, hist, flagbits,
                                                wembb, WtAd, adb, table16);
  k_scan1b<<<NB, 256, 0, stream>>>(hist, flagbits, scanA, scanB, scanC,
                                   bsumA, bsumB, bsumC);
  k_scan2p<<<1, 256, 0, stream>>>(bsumA, bsumB, bsumC, scanA, scanB, scanC, meta);
  k_scan3seg<<<B_INITP, 256, 0, stream>>>(scanA, bsumA, scanB, bsumB, scanC, bsumC,
                                          hist, flagbits, meta, segdst, segstart,
                                          seglen, rowof, zlist);
  k_setup1<<<B_PLACE + B_EMBED, 256, 0, stream>>>(et, src, dst, ew, scanA, sedge,
                                                  table16, word_ids, hb);

  // ---- t-loop (4 launches per step) ----
  for (int t = 0; t < TSTEPS; ++t) {
    const int* nsegp = &meta[32 + t];
    const int* nzp = &meta[40 + t];
    const int* ss = segstart + (long)t * N_NODES;
    const int* sl = seglen + (long)t * N_NODES;
    const int* sd = segdst + (long)t * N_NODES;
    const int* ro = rowof + (long)t * N_NODES;
    const int* zl = zlist + (long)t * N_NODES;
    const float* hxc = (t & 1) ? hxB : hxA;
    float* hxn = (t & 1) ? hxA : hxB;
    k_ls<<<B_LSTM + B_SCAT, 256, 0, stream>>>(hxc, hxn, cx, Wih, Whh, bih, bhh,
                                              meta, WtL0, WtL1, t, ss, sl, sedge,
                                              hb, P1b, nsegp);
    k_gz<<<GB + B_ZZ, 256, 0, stream>>>(P1b, WtL0, P2b, nsegp, hb, zl, nzp);
    k_s1<<<B_SCAT, 256, 0, stream>>>(ss, sl, sedge, P2b, ro, P1b, nsegp);
    k_g1<<<GB, 256, 0, stream>>>(P1b, WtL1, hb, sd, nsegp);
  }

  k_segmax<<<(N_NODES + 63) / 64, 128, 0, stream>>>(hb, gid, keys);
  k_final<<<1, 64, 0, stream>>>(keys, outW, outB, y, out);
}